// Round 21
// baseline (179.219 us; speedup 1.0000x reference)
//
#include <hip/hip_runtime.h>
#include <math.h>

#define B_ 4
#define S_ 2048
#define D_ 1024
#define E_ 16
#define DH_ 64
#define TOPK_ 8
#define MAXLEN_ 1228
#define MPAD_ 1280
#define CAPF 4.0f
#define EPS_ 1e-6f
// Q scale with log2(e) folded in: 0.125 * 1.4426950408889634
#define QSCALE_ 0.18033688011112042f

typedef __attribute__((ext_vector_type(8))) short bf16x8;
typedef __attribute__((ext_vector_type(4))) float f32x4;

__device__ inline f32x4 mfma16(bf16x8 a, bf16x8 b, f32x4 c) {
  return __builtin_amdgcn_mfma_f32_16x16x32_bf16(a, b, c, 0, 0, 0);
}
__device__ inline float bf2f(unsigned short u) {
  return __uint_as_float(((unsigned)u) << 16);
}
__device__ inline unsigned short f2bf(float f) {
  unsigned u = __float_as_uint(f);
  unsigned r = (u + 0x7FFFu + ((u >> 16) & 1u)) >> 16;
  return (unsigned short)r;
}
__device__ inline unsigned cvtpk(float lo, float hi) {
  unsigned r;
  asm("v_cvt_pk_bf16_f32 %0, %1, %2" : "=v"(r) : "v"(lo), "v"(hi));
  return r;
}
// hardware 2^x (v_exp_f32 computes exp2)
__device__ inline float exp2x(float x) {
  float r;
  asm("v_exp_f32 %0, %1" : "=v"(r) : "v"(x));
  return r;
}
__device__ inline ushort4 pk4(float4 v) {
  ushort4 r;
  r.x = f2bf(v.x); r.y = f2bf(v.y); r.z = f2bf(v.z); r.w = f2bf(v.w);
  return r;
}
// XOR-swizzled LDS addressing (byte offsets), 128B rows.
__device__ inline int swz128(int row, int off) { return row * 128 + (off ^ ((row & 7) << 4)); }

// ---------------- one-time converts ----------------
// W_qkv[e][1024 k][192 n] f32 -> Wt[e][192 n][1024 k] bf16
__global__ __launch_bounds__(256) void cvt_wqkv_kernel(
    const float* __restrict__ W, unsigned short* __restrict__ Wt) {
  __shared__ short T[192][40];
  int e = blockIdx.y, k0 = blockIdx.x * 32;
  const float* Wp = W + (size_t)e * D_ * 192 + (size_t)k0 * 192;
  int tid = threadIdx.x;
#pragma unroll
  for (int it = 0; it < 24; it++) {
    int idx = tid + it * 256;  // 0..6143
    int kr = idx / 192, n = idx % 192;
    T[n][kr] = (short)f2bf(Wp[(size_t)kr * 192 + n]);
  }
  __syncthreads();
  unsigned short* Wo = Wt + (size_t)e * 192 * 1024 + k0;
#pragma unroll
  for (int it = 0; it < 3; it++) {
    int idx = tid + it * 256;  // 0..767
    int n = idx >> 2, c = idx & 3;
    bf16x8 v = *reinterpret_cast<bf16x8*>(&T[n][c * 8]);
    *reinterpret_cast<bf16x8*>(Wo + (size_t)n * 1024 + c * 8) = v;
  }
}

// W_ff[e][64 k][1024 n] f32 -> fragment-packed Wpk[e][64 nb][2 ks][64 l][8]
__global__ __launch_bounds__(256) void cvt_wffpk_kernel(
    const float* __restrict__ W, unsigned short* __restrict__ Wpk) {
  int e = blockIdx.y;
  int nb = blockIdx.x * 4 + (threadIdx.x >> 6);
  int l = threadIdx.x & 63;
  int lr = l & 15, lg = l >> 4;
  const float* Wp = W + (size_t)e * DH_ * D_;
#pragma unroll
  for (int ks = 0; ks < 2; ks++) {
    bf16x8 v;
#pragma unroll
    for (int j = 0; j < 8; j++) {
      int k = ks * 32 + lg * 8 + j;
      int n = nb * 16 + lr;
      v[j] = (short)f2bf(Wp[(size_t)k * D_ + n]);
    }
    *reinterpret_cast<bf16x8*>(Wpk + ((((size_t)e * 64 + nb) * 2 + ks) * 64 + l) * 8) = v;
  }
}

// wg[1024 d][16 e] f32 -> wgT[16 e][1024 d] f32 (64 KB, one-time)
__global__ __launch_bounds__(256) void cvt_wgt_kernel(
    const float* __restrict__ wg, float* __restrict__ wgT) {
  int idx = blockIdx.x * 256 + threadIdx.x;  // 0..16383
  int e = idx >> 10, d = idx & 1023;
  wgT[idx] = wg[(size_t)d * E_ + e];
}

// bff[16 e][1024 n] f32 -> bffT[1024 n][32 k] bf16 (k=e for e<16, else 0)
__global__ __launch_bounds__(256) void cvt_bff_kernel(
    const float* __restrict__ bff, unsigned short* __restrict__ bffT) {
  int n = blockIdx.x * 256 + threadIdx.x;  // 0..1023
  unsigned short* o = bffT + (size_t)n * 32;
#pragma unroll
  for (int e = 0; e < E_; e++) o[e] = f2bf(bff[(size_t)e * D_ + n]);
#pragma unroll
  for (int e = E_; e < 32; e++) o[e] = 0;
}

// --------- Kernel 1: gating -> masked_t[e][b][s]; also emits Xb16 ---------
// Wave-parallel tail: lane e in [0,16) owns expert e (softmax + rank + store).
__global__ __launch_bounds__(256) void gate_kernel(
    const float* __restrict__ X, const float* __restrict__ wgT,
    const float* __restrict__ bg, float* __restrict__ masked_t,
    unsigned short* __restrict__ Xb) {
  int token = blockIdx.x * 4 + (threadIdx.x >> 6);  // b*S + s
  int lane = threadIdx.x & 63;
  int b = token / S_, s = token % S_;
  const float* xrow = X + (size_t)token * D_;
  unsigned short* xbrow = Xb + (size_t)token * D_;
  float acc[E_];
#pragma unroll
  for (int e = 0; e < E_; e++) acc[e] = 0.f;
#pragma unroll
  for (int d0 = 0; d0 < D_; d0 += 256) {
    int d = d0 + lane * 4;
    float4 xv = *reinterpret_cast<const float4*>(xrow + d);
    *reinterpret_cast<ushort4*>(xbrow + d) = pk4(xv);  // fused bf16 convert
#pragma unroll
    for (int e = 0; e < E_; e++) {
      float4 wv = *reinterpret_cast<const float4*>(wgT + (size_t)e * D_ + d);
      acc[e] += xv.x * wv.x + xv.y * wv.y + xv.z * wv.z + xv.w * wv.w;
    }
  }
#pragma unroll
  for (int e = 0; e < E_; e++) {
    float v = acc[e];
    for (int off = 32; off; off >>= 1) v += __shfl_xor(v, off);
    acc[e] = v;  // every lane now holds the full sum
  }
  // parallel tail: lane e (mod 16) handles expert e
  int e = lane & 15;
  float lg = acc[e] + bg[e];
  float mx = lg;
#pragma unroll
  for (int off = 1; off < 16; off <<= 1) mx = fmaxf(mx, __shfl_xor(mx, off));
  float ex = expf(lg - mx);
  float den = ex;
#pragma unroll
  for (int off = 1; off < 16; off <<= 1) den += __shfl_xor(den, off);
  float sc = ex / den;
  int rank = 0;
#pragma unroll
  for (int j = 0; j < 16; j++) {
    float v = __shfl(lg, (lane & 48) + j);
    if (v > lg || (v == lg && j < e)) rank++;
  }
  float m = (rank < TOPK_) ? sc : 0.f;
  if (lane < 16) masked_t[((size_t)e * B_ + b) * S_ + s] = m;
}

// ------- Kernel 3: radix-select top-MAXLEN per (e,b), route fused --------
__global__ __launch_bounds__(256) void select_kernel(
    const float* __restrict__ masked_t, int* __restrict__ seq_ids) {
  __shared__ unsigned vals[S_];
  __shared__ int hist[256];
  __shared__ int wsum[4];
  __shared__ int tsum[4];
  __shared__ unsigned sh_prefix;
  __shared__ int sh_rank;
  int eb = blockIdx.x;
  int e = eb >> 2, b = eb & 3;
  int tid = threadIdx.x;
  int lane = tid & 63, wv = tid >> 6;
  const float* mb0 = masked_t + (size_t)e * B_ * S_;
  for (int i = tid; i < S_; i += 256) {
    float v0 = mb0[i];
    float v1 = mb0[S_ + i];
    float v2 = mb0[2 * S_ + i];
    float v3 = mb0[3 * S_ + i];
    float d = EPS_;
    d += v0; d += v1; d += v2; d += v3;  // same order as route_kernel
    float mv = mb0[(size_t)b * S_ + i];
    vals[i] = __float_as_uint(mv / d * CAPF);
  }
  if (tid == 0) { sh_prefix = 0u; sh_rank = MAXLEN_; }
  __syncthreads();
  for (int shift = 24; shift >= 0; shift -= 8) {
    hist[tid] = 0;
    __syncthreads();
    unsigned pfx = sh_prefix;
    unsigned maskhi = (shift == 24) ? 0u : (0xFFFFFFFFu << (shift + 8));
    for (int i = tid; i < S_; i += 256) {
      unsigned v = vals[i];
      if ((v & maskhi) == pfx) atomicAdd(&hist[(v >> shift) & 255], 1);
    }
    __syncthreads();
    int bin = 255 - tid;
    int h = hist[bin];
    int sc = h;
    for (int off = 1; off < 64; off <<= 1) {
      int n = __shfl_up(sc, off);
      if (lane >= off) sc += n;
    }
    if (lane == 63) wsum[wv] = sc;
    __syncthreads();
    int add = 0;
#pragma unroll
    for (int k = 0; k < 4; k++)
      if (k < wv) add += wsum[k];
    sc += add;
    int rank = sh_rank;
    __syncthreads();
    if (sc - h < rank && rank <= sc) {
      sh_prefix = pfx | ((unsigned)bin << shift);
      sh_rank = rank - (sc - h);
    }
    __syncthreads();
  }
  unsigned T = sh_prefix;
  int r = sh_rank;
  int i0 = tid * 8;
  int eqf[8], gtf[8];
  int eqtot = 0;
#pragma unroll
  for (int k = 0; k < 8; k++) {
    unsigned v = vals[i0 + k];
    eqf[k] = (v == T) ? 1 : 0;
    gtf[k] = (v > T) ? 1 : 0;
    eqtot += eqf[k];
  }
  int esc = eqtot;
  for (int off = 1; off < 64; off <<= 1) {
    int n = __shfl_up(esc, off);
    if (lane >= off) esc += n;
  }
  if (lane == 63) tsum[wv] = esc;
  __syncthreads();
  int eadd = 0;
#pragma unroll
  for (int k = 0; k < 4; k++)
    if (k < wv) eadd += tsum[k];
  int erun = esc - eqtot + eadd;
  int self_[8];
  int stot = 0;
#pragma unroll
  for (int k = 0; k < 8; k++) {
    int s = gtf[k] | (eqf[k] & (erun < r ? 1 : 0));
    erun += eqf[k];
    self_[k] = s;
    stot += s;
  }
  __syncthreads();
  int ssc = stot;
  for (int off = 1; off < 64; off <<= 1) {
    int n = __shfl_up(ssc, off);
    if (lane >= off) ssc += n;
  }
  if (lane == 63) tsum[wv] = ssc;
  __syncthreads();
  int sadd = 0;
#pragma unroll
  for (int k = 0; k < 4; k++)
    if (k < wv) sadd += tsum[k];
  int pos = ssc - stot + sadd;
  int* outp = seq_ids + (size_t)eb * MAXLEN_;
#pragma unroll
  for (int k = 0; k < 8; k++) {
    if (self_[k]) outp[pos++] = i0 + k;
  }
}

// --------- Kernel 3b: inverse map inv[eb][s] = m (or -1) ---------
__global__ __launch_bounds__(256) void inv_kernel(
    const int* __restrict__ seq_ids, int* __restrict__ inv) {
  int eb = blockIdx.x;
  int tid = threadIdx.x;
  int* ip = inv + (size_t)eb * S_;
  for (int i = tid; i < S_; i += 256) ip[i] = -1;
  __syncthreads();
  const int* sid = seq_ids + (size_t)eb * MAXLEN_;
  for (int m = tid; m < MAXLEN_; m += 256) ip[sid[m]] = m;
}

// ---------------- Kernel 4: gathered QKV GEMM (bf16 MFMA) ----------------
// v6: v5 minus the rows[] LDS array (row ids loaded directly from seq_ids;
// 8 adjacent threads share each entry). LDS = 40960 B exactly -> 4 blocks/CU.
__global__ __launch_bounds__(512) void qkv_kernel(
    const unsigned short* __restrict__ Xb, const unsigned short* __restrict__ Wt,
    const int* __restrict__ seq_ids, unsigned short* __restrict__ Qr,
    unsigned short* __restrict__ Kr, unsigned short* __restrict__ VT) {
  __shared__ __align__(16) char Bs_[192 * 128];  // [192 n][64 k] bf16 swz128
  __shared__ __align__(16) char As_[128 * 128];  // [128 m][64 k] bf16 swz128
  int eb = blockIdx.y;
  int e = eb >> 2, b = eb & 3;
  int m0 = blockIdx.x * 128;
  int tid = threadIdx.x;
  int w = tid >> 6, l = tid & 63, lr = l & 15, lg = l >> 4;
  int wm = w & 3, wn = w >> 2;
  const int* sid = seq_ids + (size_t)eb * MAXLEN_;
  const unsigned short* Wm = Wt + (size_t)e * 192 * 1024;
  const unsigned short* Xbb = Xb + (size_t)b * S_ * D_;
  int b0r = tid >> 3, b0c = tid & 7;
  int b1r = (tid + 512) >> 3, b1c = b0c;
  int b2r = (tid + 1024) >> 3, b2c = b0c;
  int a0r = b0r, a0c = b0c;        // A rows 0..63
  int a1r = b1r, a1c = b0c;        // A rows 64..127
  int am0 = m0 + a0r, am1 = m0 + a1r;
  int r0 = (am0 < MAXLEN_) ? sid[am0] : 0;   // 8 threads share each entry
  int r1 = (am1 < MAXLEN_) ? sid[am1] : 0;
  const unsigned short* bpp0 = Wm + (size_t)b0r * 1024 + b0c * 8;
  const unsigned short* bpp1 = Wm + (size_t)b1r * 1024 + b1c * 8;
  const unsigned short* bpp2 = Wm + (size_t)b2r * 1024 + b2c * 8;
  const unsigned short* app0 = Xbb + (size_t)r0 * D_ + a0c * 8;
  const unsigned short* app1 = Xbb + (size_t)r1 * D_ + a1c * 8;
  f32x4 acc[2][6];
#pragma unroll
  for (int a = 0; a < 2; a++)
#pragma unroll
    for (int j = 0; j < 6; j++) acc[a][j] = (f32x4){0.f, 0.f, 0.f, 0.f};
  bf16x8 sb0 = *reinterpret_cast<const bf16x8*>(bpp0);
  bf16x8 sb1 = *reinterpret_cast<const bf16x8*>(bpp1);
  bf16x8 sb2 = *reinterpret_cast<const bf16x8*>(bpp2);
  bf16x8 sa0 = *reinterpret_cast<const bf16x8*>(app0);
  bf16x8 sa1 = *reinterpret_cast<const bf16x8*>(app1);
  for (int t = 0; t < 16; t++) {
    __syncthreads();  // readers of tile t-1 done (no-op at t=0)
    *reinterpret_cast<bf16x8*>(Bs_ + swz128(b0r, b0c * 16)) = sb0;
    *reinterpret_cast<bf16x8*>(Bs_ + swz128(b1r, b1c * 16)) = sb1;
    *reinterpret_cast<bf16x8*>(Bs_ + swz128(b2r, b2c * 16)) = sb2;
    *reinterpret_cast<bf16x8*>(As_ + swz128(a0r, a0c * 16)) = sa0;
    *reinterpret_cast<bf16x8*>(As_ + swz128(a1r, a1c * 16)) = sa1;
    __syncthreads();  // writes visible
    if (t < 15) {
      int kn = (t + 1) * 64;
      sb0 = *reinterpret_cast<const bf16x8*>(bpp0 + kn);
      sb1 = *reinterpret_cast<const bf16x8*>(bpp1 + kn);
      sb2 = *reinterpret_cast<const bf16x8*>(bpp2 + kn);
      sa0 = *reinterpret_cast<const bf16x8*>(app0 + kn);
      sa1 = *reinterpret_cast<const bf16x8*>(app1 + kn);
    }
    bf16x8 af[2][2];
#pragma unroll
    for (int a = 0; a < 2; a++)
#pragma unroll
      for (int ks = 0; ks < 2; ks++)
        af[a][ks] = *reinterpret_cast<bf16x8*>(
            As_ + swz128(wm * 32 + a * 16 + lr, ks * 64 + lg * 16));
#pragma unroll
    for (int j = 0; j < 6; j++) {
      int nr = (wn * 6 + j) * 16 + lr;
      bf16x8 bf0 = *reinterpret_cast<bf16x8*>(Bs_ + swz128(nr, lg * 16));
      bf16x8 bf1 = *reinterpret_cast<bf16x8*>(Bs_ + swz128(nr, 64 + lg * 16));
      acc[0][j] = mfma16(af[0][0], bf0, acc[0][j]);
      acc[1][j] = mfma16(af[1][0], bf0, acc[1][j]);
      acc[0][j] = mfma16(af[0][1], bf1, acc[0][j]);
      acc[1][j] = mfma16(af[1][1], bf1, acc[1][j]);
    }
  }
  unsigned short* Qe = Qr + (size_t)eb * MPAD_ * 64;
  unsigned short* Ke = Kr + (size_t)eb * MPAD_ * 64;
  unsigned short* Ve = VT + (size_t)eb * 64 * MPAD_;
#pragma unroll
  for (int a = 0; a < 2; a++) {
    int mb = m0 + wm * 32 + a * 16 + lg * 4;
#pragma unroll
    for (int j = 0; j < 6; j++) {
      int nbg = wn * 6 + j;
      if (nbg < 4) {
#pragma unroll
        for (int i = 0; i < 4; i++) {
          int m = mb + i;
          float v = (m < MAXLEN_) ? acc[a][j][i] * QSCALE_ : 0.f;
          Qe[(size_t)m * 64 + nbg * 16 + lr] = f2bf(v);
        }
      } else if (nbg < 8) {
#pragma unroll
        for (int i = 0; i < 4; i++) {
          int m = mb + i;
          float v = (m < MAXLEN_) ? acc[a][j][i] : 0.f;
          Ke[(size_t)m * 64 + (nbg - 4) * 16 + lr] = f2bf(v);
        }
      } else {
        ushort4 pv;
        pv.x = (mb + 0 < MAXLEN_) ? f2bf(acc[a][j][0]) : (unsigned short)0;
        pv.y = (mb + 1 < MAXLEN_) ? f2bf(acc[a][j][1]) : (unsigned short)0;
        pv.z = (mb + 2 < MAXLEN_) ? f2bf(acc[a][j][2]) : (unsigned short)0;
        pv.w = (mb + 3 < MAXLEN_) ? f2bf(acc[a][j][3]) : (unsigned short)0;
        *reinterpret_cast<ushort4*>(Ve + (size_t)((nbg - 8) * 16 + lr) * MPAD_ + mb) = pv;
      }
    }
  }
}

// ------------- Kernel 5: flash attention, bf16 MFMA, per (e,b) -------------
// exp2-softmax; P repack via v_cvt_pk_bf16_f32; K/V register prefetch
// across the barrier (loads for tile t+1 fly during tile-t compute).
__global__ __launch_bounds__(512) void attn_kernel(
    const unsigned short* __restrict__ Qr, const unsigned short* __restrict__ Kr,
    const unsigned short* __restrict__ VT, unsigned short* __restrict__ ctx) {
  __shared__ __align__(16) char Ks_[64 * 128];      // [64 k][64 d] swz128
  __shared__ __align__(16) char Vt_[64 * 128];      // [64 dv][64 k] swz128
  __shared__ __align__(16) char Pl_[8 * 16 * 128];  // per-wave [16 q][64 k]
  int qb = 9 - blockIdx.x;  // longest first
  int eb = blockIdx.y;
  const unsigned short* Qe = Qr + (size_t)eb * MPAD_ * 64;
  const unsigned short* Ke = Kr + (size_t)eb * MPAD_ * 64;
  const unsigned short* Ve = VT + (size_t)eb * 64 * MPAD_;
  int tid = threadIdx.x;
  int w = tid >> 6, l = tid & 63, lr = l & 15, lg = l >> 4;
  int gq = qb * 128 + w * 16 + lr;
  bf16x8 qf[2];
  qf[0] = *reinterpret_cast<const bf16x8*>(Qe + (size_t)gq * 64 + lg * 8);
  qf[1] = *reinterpret_cast<const bf16x8*>(Qe + (size_t)gq * 64 + 32 + lg * 8);
  f32x4 acc[4];
#pragma unroll
  for (int db = 0; db < 4; db++) acc[db] = (f32x4){0.f, 0.f, 0.f, 0.f};
  float mrow = -1e30f, lsum = 0.f;
  char* Pw = Pl_ + w * 2048;
  int srow = tid >> 3, sc = (tid & 7) * 8;
  int ndiag = 2 * qb, ktmax = 2 * qb + 1;
  // prologue: tile 0 into regs
  bf16x8 skv = *reinterpret_cast<const bf16x8*>(Ke + (size_t)srow * 64 + sc);
  bf16x8 svv = *reinterpret_cast<const bf16x8*>(Ve + (size_t)srow * MPAD_ + sc);
  for (int kt = 0; kt <= ktmax; kt++) {
    int k0 = kt * 64;
    __syncthreads();  // readers of tile t-1 done (no-op at kt=0)
    *reinterpret_cast<bf16x8*>(Ks_ + swz128(srow, sc * 2)) = skv;
    *reinterpret_cast<bf16x8*>(Vt_ + swz128(srow, sc * 2)) = svv;
    __syncthreads();  // writes visible
    if (kt < ktmax) {  // prefetch t+1; in flight across compute
      int kn = k0 + 64;
      skv = *reinterpret_cast<const bf16x8*>(Ke + (size_t)(kn + srow) * 64 + sc);
      svv = *reinterpret_cast<const bf16x8*>(Ve + (size_t)srow * MPAD_ + kn + sc);
    }
    f32x4 sac[4];
#pragma unroll
    for (int kb = 0; kb < 4; kb++) {
      sac[kb] = (f32x4){0.f, 0.f, 0.f, 0.f};
#pragma unroll
      for (int ds = 0; ds < 2; ds++) {
        bf16x8 kf = *reinterpret_cast<bf16x8*>(Ks_ + swz128(kb * 16 + lr, ds * 64 + lg * 16));
        sac[kb] = mfma16(kf, qf[ds], sac[kb]);
      }
    }
    float p[16];
    float tmax = -1e30f;
    if (kt >= ndiag) {
#pragma unroll
      for (int kb = 0; kb < 4; kb++) {
#pragma unroll
        for (int i = 0; i < 4; i++) {
          int k = k0 + kb * 16 + lg * 4 + i;
          float s = sac[kb][i];
          if (k > gq || k >= MAXLEN_) s = -1e9f;
          p[kb * 4 + i] = s;
          tmax = fmaxf(tmax, s);
        }
      }
    } else {
#pragma unroll
      for (int kb = 0; kb < 4; kb++) {
#pragma unroll
        for (int i = 0; i < 4; i++) {
          float s = sac[kb][i];
          p[kb * 4 + i] = s;
          tmax = fmaxf(tmax, s);
        }
      }
    }
    tmax = fmaxf(tmax, __shfl_xor(tmax, 16));
    tmax = fmaxf(tmax, __shfl_xor(tmax, 32));
    if (!__all(tmax <= mrow + 8.f)) {  // defer-rescale (log2 units)
      float mnew = fmaxf(mrow, tmax);
      float corr = exp2x(mrow - mnew);
      lsum *= corr;
#pragma unroll
      for (int db = 0; db < 4; db++) acc[db] = acc[db] * corr;
      mrow = mnew;
    }
    float psum = 0.f;
#pragma unroll
    for (int j = 0; j < 16; j++) {
      p[j] = exp2x(p[j] - mrow);
      psum += p[j];
    }
    psum += __shfl_xor(psum, 16);
    psum += __shfl_xor(psum, 32);
    lsum += psum;
#pragma unroll
    for (int kb = 0; kb < 4; kb++) {
#pragma unroll
      for (int ip = 0; ip < 2; ip++) {
        unsigned u = cvtpk(p[kb * 4 + ip * 2], p[kb * 4 + ip * 2 + 1]);
        int k = kb * 16 + lg * 4 + ip * 2;
        *reinterpret_cast<unsigned*>(Pw + swz128(lr, k * 2)) = u;
      }
    }
    bf16x8 pf[2];
#pragma unroll
    for (int ks = 0; ks < 2; ks++)
      pf[ks] = *reinterpret_cast<bf16x8*>(Pw + swz128(lr, ks * 64 + lg * 16));
#pragma unroll
    for (int db = 0; db < 4; db++) {
#pragma unroll
      for (int ks = 0; ks < 2; ks++) {
        bf16x8 vf = *reinterpret_cast<bf16x8*>(Vt_ + swz128(db * 16 + lr, ks * 64 + lg * 16));
        acc[db] = mfma16(vf, pf[ks], acc[db]);
      }
    }
  }
  if (gq < MAXLEN_) {
    float inv = 1.f / lsum;
    unsigned short* op = ctx + ((size_t)eb * MAXLEN_ + gq) * DH_;
#pragma unroll
    for (int db = 0; db < 4; db++) {
      uint2 pv;
      pv.x = cvtpk(acc[db][0] * inv, acc[db][1] * inv);
      pv.y = cvtpk(acc[db][2] * inv, acc[db][3] * inv);
      *reinterpret_cast<uint2*>(op + db * 16 + lg * 4) = pv;
    }
  }
}

// --- Kernel 6: fused FF + expert-sum + residual + LayerNorm ---
// v4 (R15): ALL experts' A-tiles staged to LDS up front (64KB, one barrier),
// then the 16-expert MFMA loop runs with ZERO barriers.
__global__ __launch_bounds__(1024) void ffgl_kernel(
    const float* __restrict__ X, const unsigned short* __restrict__ ctx,
    const unsigned short* __restrict__ Wpk, const unsigned short* __restrict__ bffT,
    const int* __restrict__ inv, const float* __restrict__ gamma,
    const float* __restrict__ beta, float* __restrict__ out) {
  __shared__ int invs[E_][32];
  __shared__ __align__(16) char Ae_[E_ * 32 * 128];  // 64 KB
  __shared__ float red1[16][32], red2[16][32];
  __shared__ float mu_s[32], ri_s[32];
  int st = blockIdx.x, b = blockIdx.y;
  int s0 = st * 32;
  int tid = threadIdx.x;
  int w = tid >> 6, l = tid & 63, lr = l & 15, lg = l >> 4;
  if (tid < 512) {
    int e = tid >> 5, i = tid & 31;
    invs[e][i] = inv[((size_t)(e * B_ + b)) * S_ + s0 + i];
  }
  __syncthreads();
  // stage all experts' A tiles: 4096 x 16B chunks, coalesced per row
#pragma unroll
  for (int p = 0; p < 4; p++) {
    int idx = p * 1024 + tid;
    int e = idx >> 8, rem = idx & 255;
    int row = rem >> 3, c = rem & 7;
    int m = invs[e][row];
    bf16x8 v;
    if (m >= 0) {
      v = *reinterpret_cast<const bf16x8*>(
          ctx + ((size_t)(e * B_ + b) * MAXLEN_ + m) * DH_ + c * 8);
    } else {
#pragma unroll
      for (int t = 0; t < 8; t++) v[t] = 0;
    }
    *reinterpret_cast<bf16x8*>(Ae_ + e * 4096 + swz128(row, c * 16)) = v;
  }
  __syncthreads();
  f32x4 acc[2][4];
#pragma unroll
  for (int a = 0; a < 2; a++)
#pragma unroll
    for (int j = 0; j < 4; j++) acc[a][j] = (f32x4){0.f, 0.f, 0.f, 0.f};
#pragma unroll 1
  for (int e = 0; e < E_; e++) {
    const char* Ab = Ae_ + e * 4096;
    bf16x8 af[2][2];
#pragma unroll
    for (int a = 0; a < 2; a++)
#pragma unroll
      for (int ks = 0; ks < 2; ks++)
        af[a][ks] = *reinterpret_cast<const bf16x8*>(
            Ab + swz128(a * 16 + lr, ks * 64 + lg * 16));
    const unsigned short* We = Wpk + (size_t)e * 65536;
#pragma unroll
    for (int j = 0; j < 4; j++) {
      int nbi = w * 4 + j;
      bf16x8 b0 = *reinterpret_cast<const bf16x8*>(We + (((size_t)nbi * 2 + 0) * 64 + l) * 8);
      bf16x8 b1 = *reinterpret_cast<const bf16x8*>(We + (((size_t)nbi * 2 + 1) * 64 + l) * 8);
      acc[0][j] = mfma16(af[0][0], b0, acc[0][j]);
      acc[1][j] = mfma16(af[1][0], b0, acc[1][j]);
      acc[0][j] = mfma16(af[0][1], b1, acc[0][j]);
      acc[1][j] = mfma16(af[1][1], b1, acc[1][j]);
    }
  }
  {
    bf16x8 afb[2];
#pragma unroll
    for (int a = 0; a < 2; a++) {
#pragma unroll
      for (int t = 0; t < 8; t++) {
        int k = lg * 8 + t;
        unsigned short u = 0;
        if (k < E_ && invs[k][a * 16 + lr] >= 0) u = 0x3F80;  // 1.0bf16
        afb[a][t] = (short)u;
      }
    }
#pragma unroll
    for (int j = 0; j < 4; j++) {
      int n = w * 64 + j * 16 + lr;
      bf16x8 bb = *reinterpret_cast<const bf16x8*>(bffT + (size_t)n * 32 + lg * 8);
      acc[0][j] = mfma16(afb[0], bb, acc[0][j]);
      acc[1][j] = mfma16(afb[1], bb, acc[1][j]);
    }
  }
  // epilogue: + X residual (loaded here), row stats, LayerNorm, store f32
  float p1[2][4], p2[2][4];
#pragma unroll
  for (int a = 0; a < 2; a++)
#pragma unroll
    for (int i = 0; i < 4; i++) { p1[a][i] = 0.f; p2[a][i] = 0.f; }
#pragma unroll
  for (int a = 0; a < 2; a++) {
#pragma unroll
    for (int j = 0; j < 4; j++) {
      int col = w * 64 + j * 16 + lr;
#pragma unroll
      for (int i = 0; i < 4; i++) {
        int row = a * 16 + lg * 4 + i;
        float x = X[((size_t)b * S_ + s0 + row) * D_ + col];
        float v = acc[a][j][i] + x;
        acc[a][j][i] = v;
        p1[a][i] += v;
        p2[a][i] += v * v;
      }
    }
  }
#pragma unroll
  for (int a = 0; a < 2; a++)
#pragma unroll
    for (int i = 0; i < 4; i++) {
#pragma unroll
      for (int off = 1; off < 16; off <<= 1) {
        p1[a][i] += __shfl_xor(p1[a][i], off);
        p2[a][i] += __shfl_xor(p2[a][i], off);
      }
    }
  if (lr == 0) {
#pragma unroll
    for (int a = 0; a < 2; a++)
#pragma unroll
      for (int i = 0; i < 4; i++) {
        int row = a * 16 + lg * 4 + i;
        red1[w][row] = p1[a][i];
        red2[w][row] = p2[a][i];
      }
  }
  __syncthreads();
  if (tid < 32) {
    float s1 = 0.f, s2 = 0.f;
#pragma unroll
    for (int w2 = 0; w2 < 16; w2++) { s1 += red1[w2][tid]; s2 += red2[w2][tid]; }
    float mu = s1 * (1.f / D_);
    float var = s2 * (1.f / D_) - mu * mu;
    mu_s[tid] = mu;
    ri_s[tid] = rsqrtf(var + 1e-5f);
  }
  __syncthreads();
#pragma unroll
  for (int a = 0; a < 2; a++) {
#pragma unroll
    for (int j = 0; j < 4; j++) {
      int col = w * 64 + j * 16 + lr;
      float g = gamma[col];
      float be = beta[col];
#pragma unroll
      for (int i = 0; i < 4; i++) {
        int row = a * 16 + lg * 4 + i;
        out[((size_t)b * S_ + s0 + row) * D_ + col] =
            (acc[a][j][i] - mu_s[row]) * ri_s[row] * g + be;
      }
    }
  }
}

extern "C" void kernel_launch(void* const* d_in, const int* in_sizes, int n_in,
                              void* d_out, int out_size, void* d_ws, size_t ws_size,
                              hipStream_t stream) {
  const float* X = (const float*)d_in[0];
  // d_in[1] = attn_mask (causal, hardcoded)
  const float* w_gate = (const float*)d_in[2];
  const float* b_gate = (const float*)d_in[3];
  const float* W_qkv = (const float*)d_in[4];
  const float* W_ff = (const float*)d_in[5];
  const float* b_ff = (const float*)d_in[6];
  const float* ln_g = (const float*)d_in[7];
  const float* ln_b = (const float*)d_in[8];
  float* out = (float*)d_out;

  char* ws = (char*)d_ws;
  float* masked_t = (float*)(ws);                           //   524288 B
  int* seq_ids = (int*)(ws + 1048576);                      //   314368 B
  unsigned short* Qr = (unsigned short*)(ws + 1362944);     // 10485760 B
  unsigned short* Kr = (unsigned short*)(ws + 11848704);    // 10485760 B
  unsigned short* VT = (unsigned short*)(ws + 22334464);    // 10485760 B
  unsigned short* ctx = (unsigned short*)(ws + 32820224);   // 10059776 B
  unsigned short* Xb16 = (unsigned short*)(ws + 42880000);  // 16777216 B
  unsigned short* Wtq = (unsigned short*)(ws + 59657216);   //  6291456 B
  unsigned short* Wpk = (unsigned short*)(ws + 65948672);   //  2097152 B
  float* wgT = (float*)(ws + 68045824);                     //    65536 B
  unsigned short* bffT = (unsigned short*)(ws + 68111360);  //    65536 B
  int* inv = (int*)(ws + 68176896);                         //   524288 B
  // total 68701184 B

  cvt_wqkv_kernel<<<dim3(32, 16), 256, 0, stream>>>(W_qkv, Wtq);
  cvt_wffpk_kernel<<<dim3(16, 16), 256, 0, stream>>>(W_ff, Wpk);
  cvt_wgt_kernel<<<64, 256, 0, stream>>>(w_gate, wgT);
  cvt_bff_kernel<<<4, 256, 0, stream>>>(b_ff, bffT);
  gate_kernel<<<2048, 256, 0, stream>>>(X, wgT, b_gate, masked_t, Xb16);
  select_kernel<<<E_ * B_, 256, 0, stream>>>(masked_t, seq_ids);
  inv_kernel<<<E_ * B_, 256, 0, stream>>>(seq_ids, inv);
  qkv_kernel<<<dim3(10, 64), 512, 0, stream>>>(Xb16, Wtq, seq_ids, Qr, Kr, VT);
  attn_kernel<<<dim3(10, 64), 512, 0, stream>>>(Qr, Kr, VT, ctx);
  ffgl_kernel<<<dim3(S_ / 32, B_), 1024, 0, stream>>>(X, ctx, Wpk, bffT, inv,
                                                      ln_g, ln_b, out);
}

// Round 22
// 171.218 us; speedup vs baseline: 1.0467x; 1.0467x over previous
//
#include <hip/hip_runtime.h>
#include <math.h>

#define B_ 4
#define S_ 2048
#define D_ 1024
#define E_ 16
#define DH_ 64
#define TOPK_ 8
#define MAXLEN_ 1228
#define MPAD_ 1280
#define CAPF 4.0f
#define EPS_ 1e-6f
// Q scale with log2(e) folded in: 0.125 * 1.4426950408889634
#define QSCALE_ 0.18033688011112042f

typedef __attribute__((ext_vector_type(8))) short bf16x8;
typedef __attribute__((ext_vector_type(4))) float f32x4;

__device__ inline f32x4 mfma16(bf16x8 a, bf16x8 b, f32x4 c) {
  return __builtin_amdgcn_mfma_f32_16x16x32_bf16(a, b, c, 0, 0, 0);
}
__device__ inline float bf2f(unsigned short u) {
  return __uint_as_float(((unsigned)u) << 16);
}
__device__ inline unsigned short f2bf(float f) {
  unsigned u = __float_as_uint(f);
  unsigned r = (u + 0x7FFFu + ((u >> 16) & 1u)) >> 16;
  return (unsigned short)r;
}
__device__ inline unsigned cvtpk(float lo, float hi) {
  unsigned r;
  asm("v_cvt_pk_bf16_f32 %0, %1, %2" : "=v"(r) : "v"(lo), "v"(hi));
  return r;
}
// hardware 2^x (v_exp_f32 computes exp2)
__device__ inline float exp2x(float x) {
  float r;
  asm("v_exp_f32 %0, %1" : "=v"(r) : "v"(x));
  return r;
}
__device__ inline ushort4 pk4(float4 v) {
  ushort4 r;
  r.x = f2bf(v.x); r.y = f2bf(v.y); r.z = f2bf(v.z); r.w = f2bf(v.w);
  return r;
}
// XOR-swizzled LDS addressing (byte offsets), 128B rows.
__device__ inline int swz128(int row, int off) { return row * 128 + (off ^ ((row & 7) << 4)); }

// ---------------- fused one-time converts (one launch) ----------------
// blocks [0,512):   W_qkv -> Wt  (e = lin>>5, k0 = (lin&31)*32)
// blocks [512,768): W_ff  -> Wpk (e = l2>>4, nbgrp = l2&15)
// blocks [768,832): wg -> wgT
// blocks [832,836): bff -> bffT
__global__ __launch_bounds__(256) void cvt_all_kernel(
    const float* __restrict__ Wq, unsigned short* __restrict__ Wt,
    const float* __restrict__ Wf, unsigned short* __restrict__ Wpk,
    const float* __restrict__ wg, float* __restrict__ wgT,
    const float* __restrict__ bff, unsigned short* __restrict__ bffT) {
  __shared__ short T[192][40];
  int bid = blockIdx.x;
  int tid = threadIdx.x;
  if (bid < 512) {
    int e = bid >> 5, k0 = (bid & 31) * 32;
    const float* Wp = Wq + (size_t)e * D_ * 192 + (size_t)k0 * 192;
#pragma unroll
    for (int it = 0; it < 24; it++) {
      int idx = tid + it * 256;  // 0..6143
      int kr = idx / 192, n = idx % 192;
      T[n][kr] = (short)f2bf(Wp[(size_t)kr * 192 + n]);
    }
    __syncthreads();
    unsigned short* Wo = Wt + (size_t)e * 192 * 1024 + k0;
#pragma unroll
    for (int it = 0; it < 3; it++) {
      int idx = tid + it * 256;  // 0..767
      int n = idx >> 2, c = idx & 3;
      bf16x8 v = *reinterpret_cast<bf16x8*>(&T[n][c * 8]);
      *reinterpret_cast<bf16x8*>(Wo + (size_t)n * 1024 + c * 8) = v;
    }
  } else if (bid < 768) {
    int l2 = bid - 512;
    int e = l2 >> 4;
    int nb = (l2 & 15) * 4 + (tid >> 6);
    int l = tid & 63;
    int lr = l & 15, lg = l >> 4;
    const float* Wp = Wf + (size_t)e * DH_ * D_;
#pragma unroll
    for (int ks = 0; ks < 2; ks++) {
      bf16x8 v;
#pragma unroll
      for (int j = 0; j < 8; j++) {
        int k = ks * 32 + lg * 8 + j;
        int n = nb * 16 + lr;
        v[j] = (short)f2bf(Wp[(size_t)k * D_ + n]);
      }
      *reinterpret_cast<bf16x8*>(Wpk + ((((size_t)e * 64 + nb) * 2 + ks) * 64 + l) * 8) = v;
    }
  } else if (bid < 832) {
    int idx = (bid - 768) * 256 + tid;  // 0..16383
    int e = idx >> 10, d = idx & 1023;
    wgT[idx] = wg[(size_t)d * E_ + e];
  } else {
    int n = (bid - 832) * 256 + tid;  // 0..1023
    unsigned short* o = bffT + (size_t)n * 32;
#pragma unroll
    for (int e = 0; e < E_; e++) o[e] = f2bf(bff[(size_t)e * D_ + n]);
#pragma unroll
    for (int e = E_; e < 32; e++) o[e] = 0;
  }
}

// --------- Kernel 1: gating -> masked_t[e][b][s]; also emits Xb16 ---------
// Wave-parallel tail: lane e in [0,16) owns expert e (softmax + rank + store).
__global__ __launch_bounds__(256) void gate_kernel(
    const float* __restrict__ X, const float* __restrict__ wgT,
    const float* __restrict__ bg, float* __restrict__ masked_t,
    unsigned short* __restrict__ Xb) {
  int token = blockIdx.x * 4 + (threadIdx.x >> 6);  // b*S + s
  int lane = threadIdx.x & 63;
  int b = token / S_, s = token % S_;
  const float* xrow = X + (size_t)token * D_;
  unsigned short* xbrow = Xb + (size_t)token * D_;
  float acc[E_];
#pragma unroll
  for (int e = 0; e < E_; e++) acc[e] = 0.f;
#pragma unroll
  for (int d0 = 0; d0 < D_; d0 += 256) {
    int d = d0 + lane * 4;
    float4 xv = *reinterpret_cast<const float4*>(xrow + d);
    *reinterpret_cast<ushort4*>(xbrow + d) = pk4(xv);  // fused bf16 convert
#pragma unroll
    for (int e = 0; e < E_; e++) {
      float4 wv = *reinterpret_cast<const float4*>(wgT + (size_t)e * D_ + d);
      acc[e] += xv.x * wv.x + xv.y * wv.y + xv.z * wv.z + xv.w * wv.w;
    }
  }
#pragma unroll
  for (int e = 0; e < E_; e++) {
    float v = acc[e];
    for (int off = 32; off; off >>= 1) v += __shfl_xor(v, off);
    acc[e] = v;  // every lane now holds the full sum
  }
  // parallel tail: lane e (mod 16) handles expert e
  int e = lane & 15;
  float lg = acc[e] + bg[e];
  float mx = lg;
#pragma unroll
  for (int off = 1; off < 16; off <<= 1) mx = fmaxf(mx, __shfl_xor(mx, off));
  float ex = expf(lg - mx);
  float den = ex;
#pragma unroll
  for (int off = 1; off < 16; off <<= 1) den += __shfl_xor(den, off);
  float sc = ex / den;
  int rank = 0;
#pragma unroll
  for (int j = 0; j < 16; j++) {
    float v = __shfl(lg, (lane & 48) + j);
    if (v > lg || (v == lg && j < e)) rank++;
  }
  float m = (rank < TOPK_) ? sc : 0.f;
  if (lane < 16) masked_t[((size_t)e * B_ + b) * S_ + s] = m;
}

// ------- Kernel 3: radix-select top-MAXLEN per (e,b), route fused ------
// Also writes inv[eb][s] = m (or -1) directly (inv_kernel folded in).
__global__ __launch_bounds__(256) void select_kernel(
    const float* __restrict__ masked_t, int* __restrict__ seq_ids,
    int* __restrict__ inv) {
  __shared__ unsigned vals[S_];
  __shared__ int hist[256];
  __shared__ int wsum[4];
  __shared__ int tsum[4];
  __shared__ unsigned sh_prefix;
  __shared__ int sh_rank;
  int eb = blockIdx.x;
  int e = eb >> 2, b = eb & 3;
  int tid = threadIdx.x;
  int lane = tid & 63, wv = tid >> 6;
  const float* mb0 = masked_t + (size_t)e * B_ * S_;
  for (int i = tid; i < S_; i += 256) {
    float v0 = mb0[i];
    float v1 = mb0[S_ + i];
    float v2 = mb0[2 * S_ + i];
    float v3 = mb0[3 * S_ + i];
    float d = EPS_;
    d += v0; d += v1; d += v2; d += v3;  // same order as route_kernel
    float mv = mb0[(size_t)b * S_ + i];
    vals[i] = __float_as_uint(mv / d * CAPF);
  }
  if (tid == 0) { sh_prefix = 0u; sh_rank = MAXLEN_; }
  __syncthreads();
  for (int shift = 24; shift >= 0; shift -= 8) {
    hist[tid] = 0;
    __syncthreads();
    unsigned pfx = sh_prefix;
    unsigned maskhi = (shift == 24) ? 0u : (0xFFFFFFFFu << (shift + 8));
    for (int i = tid; i < S_; i += 256) {
      unsigned v = vals[i];
      if ((v & maskhi) == pfx) atomicAdd(&hist[(v >> shift) & 255], 1);
    }
    __syncthreads();
    int bin = 255 - tid;
    int h = hist[bin];
    int sc = h;
    for (int off = 1; off < 64; off <<= 1) {
      int n = __shfl_up(sc, off);
      if (lane >= off) sc += n;
    }
    if (lane == 63) wsum[wv] = sc;
    __syncthreads();
    int add = 0;
#pragma unroll
    for (int k = 0; k < 4; k++)
      if (k < wv) add += wsum[k];
    sc += add;
    int rank = sh_rank;
    __syncthreads();
    if (sc - h < rank && rank <= sc) {
      sh_prefix = pfx | ((unsigned)bin << shift);
      sh_rank = rank - (sc - h);
    }
    __syncthreads();
  }
  unsigned T = sh_prefix;
  int r = sh_rank;
  int i0 = tid * 8;
  int eqf[8], gtf[8];
  int eqtot = 0;
#pragma unroll
  for (int k = 0; k < 8; k++) {
    unsigned v = vals[i0 + k];
    eqf[k] = (v == T) ? 1 : 0;
    gtf[k] = (v > T) ? 1 : 0;
    eqtot += eqf[k];
  }
  int esc = eqtot;
  for (int off = 1; off < 64; off <<= 1) {
    int n = __shfl_up(esc, off);
    if (lane >= off) esc += n;
  }
  if (lane == 63) tsum[wv] = esc;
  __syncthreads();
  int eadd = 0;
#pragma unroll
  for (int k = 0; k < 4; k++)
    if (k < wv) eadd += tsum[k];
  int erun = esc - eqtot + eadd;
  int self_[8];
  int stot = 0;
#pragma unroll
  for (int k = 0; k < 8; k++) {
    int s = gtf[k] | (eqf[k] & (erun < r ? 1 : 0));
    erun += eqf[k];
    self_[k] = s;
    stot += s;
  }
  __syncthreads();
  int ssc = stot;
  for (int off = 1; off < 64; off <<= 1) {
    int n = __shfl_up(ssc, off);
    if (lane >= off) ssc += n;
  }
  if (lane == 63) tsum[wv] = ssc;
  __syncthreads();
  int sadd = 0;
#pragma unroll
  for (int k = 0; k < 4; k++)
    if (k < wv) sadd += tsum[k];
  int pos = ssc - stot + sadd;
  int* outp = seq_ids + (size_t)eb * MAXLEN_;
  int* ip = inv + (size_t)eb * S_;
#pragma unroll
  for (int k = 0; k < 8; k++) {
    if (self_[k]) {
      outp[pos] = i0 + k;
      ip[i0 + k] = pos;
      pos++;
    } else {
      ip[i0 + k] = -1;
    }
  }
}

// ---------------- Kernel 4: gathered QKV GEMM (bf16 MFMA) ----------------
// v6 (R20): A+B staged through LDS (40 KB), single-buffered, register
// prefetch across the barrier; row ids loaded directly from seq_ids.
__global__ __launch_bounds__(512) void qkv_kernel(
    const unsigned short* __restrict__ Xb, const unsigned short* __restrict__ Wt,
    const int* __restrict__ seq_ids, unsigned short* __restrict__ Qr,
    unsigned short* __restrict__ Kr, unsigned short* __restrict__ VT) {
  __shared__ __align__(16) char Bs_[192 * 128];  // [192 n][64 k] bf16 swz128
  __shared__ __align__(16) char As_[128 * 128];  // [128 m][64 k] bf16 swz128
  int eb = blockIdx.y;
  int e = eb >> 2, b = eb & 3;
  int m0 = blockIdx.x * 128;
  int tid = threadIdx.x;
  int w = tid >> 6, l = tid & 63, lr = l & 15, lg = l >> 4;
  int wm = w & 3, wn = w >> 2;
  const int* sid = seq_ids + (size_t)eb * MAXLEN_;
  const unsigned short* Wm = Wt + (size_t)e * 192 * 1024;
  const unsigned short* Xbb = Xb + (size_t)b * S_ * D_;
  int b0r = tid >> 3, b0c = tid & 7;
  int b1r = (tid + 512) >> 3, b1c = b0c;
  int b2r = (tid + 1024) >> 3, b2c = b0c;
  int a0r = b0r, a0c = b0c;        // A rows 0..63
  int a1r = b1r, a1c = b0c;        // A rows 64..127
  int am0 = m0 + a0r, am1 = m0 + a1r;
  int r0 = (am0 < MAXLEN_) ? sid[am0] : 0;   // 8 threads share each entry
  int r1 = (am1 < MAXLEN_) ? sid[am1] : 0;
  const unsigned short* bpp0 = Wm + (size_t)b0r * 1024 + b0c * 8;
  const unsigned short* bpp1 = Wm + (size_t)b1r * 1024 + b1c * 8;
  const unsigned short* bpp2 = Wm + (size_t)b2r * 1024 + b2c * 8;
  const unsigned short* app0 = Xbb + (size_t)r0 * D_ + a0c * 8;
  const unsigned short* app1 = Xbb + (size_t)r1 * D_ + a1c * 8;
  f32x4 acc[2][6];
#pragma unroll
  for (int a = 0; a < 2; a++)
#pragma unroll
    for (int j = 0; j < 6; j++) acc[a][j] = (f32x4){0.f, 0.f, 0.f, 0.f};
  bf16x8 sb0 = *reinterpret_cast<const bf16x8*>(bpp0);
  bf16x8 sb1 = *reinterpret_cast<const bf16x8*>(bpp1);
  bf16x8 sb2 = *reinterpret_cast<const bf16x8*>(bpp2);
  bf16x8 sa0 = *reinterpret_cast<const bf16x8*>(app0);
  bf16x8 sa1 = *reinterpret_cast<const bf16x8*>(app1);
  for (int t = 0; t < 16; t++) {
    __syncthreads();  // readers of tile t-1 done (no-op at t=0)
    *reinterpret_cast<bf16x8*>(Bs_ + swz128(b0r, b0c * 16)) = sb0;
    *reinterpret_cast<bf16x8*>(Bs_ + swz128(b1r, b1c * 16)) = sb1;
    *reinterpret_cast<bf16x8*>(Bs_ + swz128(b2r, b2c * 16)) = sb2;
    *reinterpret_cast<bf16x8*>(As_ + swz128(a0r, a0c * 16)) = sa0;
    *reinterpret_cast<bf16x8*>(As_ + swz128(a1r, a1c * 16)) = sa1;
    __syncthreads();  // writes visible
    if (t < 15) {
      int kn = (t + 1) * 64;
      sb0 = *reinterpret_cast<const bf16x8*>(bpp0 + kn);
      sb1 = *reinterpret_cast<const bf16x8*>(bpp1 + kn);
      sb2 = *reinterpret_cast<const bf16x8*>(bpp2 + kn);
      sa0 = *reinterpret_cast<const bf16x8*>(app0 + kn);
      sa1 = *reinterpret_cast<const bf16x8*>(app1 + kn);
    }
    bf16x8 af[2][2];
#pragma unroll
    for (int a = 0; a < 2; a++)
#pragma unroll
      for (int ks = 0; ks < 2; ks++)
        af[a][ks] = *reinterpret_cast<bf16x8*>(
            As_ + swz128(wm * 32 + a * 16 + lr, ks * 64 + lg * 16));
#pragma unroll
    for (int j = 0; j < 6; j++) {
      int nr = (wn * 6 + j) * 16 + lr;
      bf16x8 bf0 = *reinterpret_cast<bf16x8*>(Bs_ + swz128(nr, lg * 16));
      bf16x8 bf1 = *reinterpret_cast<bf16x8*>(Bs_ + swz128(nr, 64 + lg * 16));
      acc[0][j] = mfma16(af[0][0], bf0, acc[0][j]);
      acc[1][j] = mfma16(af[1][0], bf0, acc[1][j]);
      acc[0][j] = mfma16(af[0][1], bf1, acc[0][j]);
      acc[1][j] = mfma16(af[1][1], bf1, acc[1][j]);
    }
  }
  unsigned short* Qe = Qr + (size_t)eb * MPAD_ * 64;
  unsigned short* Ke = Kr + (size_t)eb * MPAD_ * 64;
  unsigned short* Ve = VT + (size_t)eb * 64 * MPAD_;
#pragma unroll
  for (int a = 0; a < 2; a++) {
    int mb = m0 + wm * 32 + a * 16 + lg * 4;
#pragma unroll
    for (int j = 0; j < 6; j++) {
      int nbg = wn * 6 + j;
      if (nbg < 4) {
#pragma unroll
        for (int i = 0; i < 4; i++) {
          int m = mb + i;
          float v = (m < MAXLEN_) ? acc[a][j][i] * QSCALE_ : 0.f;
          Qe[(size_t)m * 64 + nbg * 16 + lr] = f2bf(v);
        }
      } else if (nbg < 8) {
#pragma unroll
        for (int i = 0; i < 4; i++) {
          int m = mb + i;
          float v = (m < MAXLEN_) ? acc[a][j][i] : 0.f;
          Ke[(size_t)m * 64 + (nbg - 4) * 16 + lr] = f2bf(v);
        }
      } else {
        ushort4 pv;
        pv.x = (mb + 0 < MAXLEN_) ? f2bf(acc[a][j][0]) : (unsigned short)0;
        pv.y = (mb + 1 < MAXLEN_) ? f2bf(acc[a][j][1]) : (unsigned short)0;
        pv.z = (mb + 2 < MAXLEN_) ? f2bf(acc[a][j][2]) : (unsigned short)0;
        pv.w = (mb + 3 < MAXLEN_) ? f2bf(acc[a][j][3]) : (unsigned short)0;
        *reinterpret_cast<ushort4*>(Ve + (size_t)((nbg - 8) * 16 + lr) * MPAD_ + mb) = pv;
      }
    }
  }
}

// ------------- Kernel 5: flash attention, bf16 MFMA, per (e,b) -------------
// exp2-softmax; P repack via v_cvt_pk_bf16_f32; K/V register prefetch
// across the barrier (loads for tile t+1 fly during tile-t compute).
__global__ __launch_bounds__(512) void attn_kernel(
    const unsigned short* __restrict__ Qr, const unsigned short* __restrict__ Kr,
    const unsigned short* __restrict__ VT, unsigned short* __restrict__ ctx) {
  __shared__ __align__(16) char Ks_[64 * 128];      // [64 k][64 d] swz128
  __shared__ __align__(16) char Vt_[64 * 128];      // [64 dv][64 k] swz128
  __shared__ __align__(16) char Pl_[8 * 16 * 128];  // per-wave [16 q][64 k]
  int qb = 9 - blockIdx.x;  // longest first
  int eb = blockIdx.y;
  const unsigned short* Qe = Qr + (size_t)eb * MPAD_ * 64;
  const unsigned short* Ke = Kr + (size_t)eb * MPAD_ * 64;
  const unsigned short* Ve = VT + (size_t)eb * 64 * MPAD_;
  int tid = threadIdx.x;
  int w = tid >> 6, l = tid & 63, lr = l & 15, lg = l >> 4;
  int gq = qb * 128 + w * 16 + lr;
  bf16x8 qf[2];
  qf[0] = *reinterpret_cast<const bf16x8*>(Qe + (size_t)gq * 64 + lg * 8);
  qf[1] = *reinterpret_cast<const bf16x8*>(Qe + (size_t)gq * 64 + 32 + lg * 8);
  f32x4 acc[4];
#pragma unroll
  for (int db = 0; db < 4; db++) acc[db] = (f32x4){0.f, 0.f, 0.f, 0.f};
  float mrow = -1e30f, lsum = 0.f;
  char* Pw = Pl_ + w * 2048;
  int srow = tid >> 3, sc = (tid & 7) * 8;
  int ndiag = 2 * qb, ktmax = 2 * qb + 1;
  // prologue: tile 0 into regs
  bf16x8 skv = *reinterpret_cast<const bf16x8*>(Ke + (size_t)srow * 64 + sc);
  bf16x8 svv = *reinterpret_cast<const bf16x8*>(Ve + (size_t)srow * MPAD_ + sc);
  for (int kt = 0; kt <= ktmax; kt++) {
    int k0 = kt * 64;
    __syncthreads();  // readers of tile t-1 done (no-op at kt=0)
    *reinterpret_cast<bf16x8*>(Ks_ + swz128(srow, sc * 2)) = skv;
    *reinterpret_cast<bf16x8*>(Vt_ + swz128(srow, sc * 2)) = svv;
    __syncthreads();  // writes visible
    if (kt < ktmax) {  // prefetch t+1; in flight across compute
      int kn = k0 + 64;
      skv = *reinterpret_cast<const bf16x8*>(Ke + (size_t)(kn + srow) * 64 + sc);
      svv = *reinterpret_cast<const bf16x8*>(Ve + (size_t)srow * MPAD_ + kn + sc);
    }
    f32x4 sac[4];
#pragma unroll
    for (int kb = 0; kb < 4; kb++) {
      sac[kb] = (f32x4){0.f, 0.f, 0.f, 0.f};
#pragma unroll
      for (int ds = 0; ds < 2; ds++) {
        bf16x8 kf = *reinterpret_cast<bf16x8*>(Ks_ + swz128(kb * 16 + lr, ds * 64 + lg * 16));
        sac[kb] = mfma16(kf, qf[ds], sac[kb]);
      }
    }
    float p[16];
    float tmax = -1e30f;
    if (kt >= ndiag) {
#pragma unroll
      for (int kb = 0; kb < 4; kb++) {
#pragma unroll
        for (int i = 0; i < 4; i++) {
          int k = k0 + kb * 16 + lg * 4 + i;
          float s = sac[kb][i];
          if (k > gq || k >= MAXLEN_) s = -1e9f;
          p[kb * 4 + i] = s;
          tmax = fmaxf(tmax, s);
        }
      }
    } else {
#pragma unroll
      for (int kb = 0; kb < 4; kb++) {
#pragma unroll
        for (int i = 0; i < 4; i++) {
          float s = sac[kb][i];
          p[kb * 4 + i] = s;
          tmax = fmaxf(tmax, s);
        }
      }
    }
    tmax = fmaxf(tmax, __shfl_xor(tmax, 16));
    tmax = fmaxf(tmax, __shfl_xor(tmax, 32));
    if (!__all(tmax <= mrow + 8.f)) {  // defer-rescale (log2 units)
      float mnew = fmaxf(mrow, tmax);
      float corr = exp2x(mrow - mnew);
      lsum *= corr;
#pragma unroll
      for (int db = 0; db < 4; db++) acc[db] = acc[db] * corr;
      mrow = mnew;
    }
    float psum = 0.f;
#pragma unroll
    for (int j = 0; j < 16; j++) {
      p[j] = exp2x(p[j] - mrow);
      psum += p[j];
    }
    psum += __shfl_xor(psum, 16);
    psum += __shfl_xor(psum, 32);
    lsum += psum;
#pragma unroll
    for (int kb = 0; kb < 4; kb++) {
#pragma unroll
      for (int ip = 0; ip < 2; ip++) {
        unsigned u = cvtpk(p[kb * 4 + ip * 2], p[kb * 4 + ip * 2 + 1]);
        int k = kb * 16 + lg * 4 + ip * 2;
        *reinterpret_cast<unsigned*>(Pw + swz128(lr, k * 2)) = u;
      }
    }
    bf16x8 pf[2];
#pragma unroll
    for (int ks = 0; ks < 2; ks++)
      pf[ks] = *reinterpret_cast<bf16x8*>(Pw + swz128(lr, ks * 64 + lg * 16));
#pragma unroll
    for (int db = 0; db < 4; db++) {
#pragma unroll
      for (int ks = 0; ks < 2; ks++) {
        bf16x8 vf = *reinterpret_cast<bf16x8*>(Vt_ + swz128(db * 16 + lr, ks * 64 + lg * 16));
        acc[db] = mfma16(vf, pf[ks], acc[db]);
      }
    }
  }
  if (gq < MAXLEN_) {
    float inv = 1.f / lsum;
    unsigned short* op = ctx + ((size_t)eb * MAXLEN_ + gq) * DH_;
#pragma unroll
    for (int db = 0; db < 4; db++) {
      uint2 pv;
      pv.x = cvtpk(acc[db][0] * inv, acc[db][1] * inv);
      pv.y = cvtpk(acc[db][2] * inv, acc[db][3] * inv);
      *reinterpret_cast<uint2*>(op + db * 16 + lg * 4) = pv;
    }
  }
}

// --- Kernel 6: fused FF + expert-sum + residual + LayerNorm ---
// v4 (R15): ALL experts' A-tiles staged to LDS up front (64KB, one barrier),
// then the 16-expert MFMA loop runs with ZERO barriers.
__global__ __launch_bounds__(1024) void ffgl_kernel(
    const float* __restrict__ X, const unsigned short* __restrict__ ctx,
    const unsigned short* __restrict__ Wpk, const unsigned short* __restrict__ bffT,
    const int* __restrict__ inv, const float* __restrict__ gamma,
    const float* __restrict__ beta, float* __restrict__ out) {
  __shared__ int invs[E_][32];
  __shared__ __align__(16) char Ae_[E_ * 32 * 128];  // 64 KB
  __shared__ float red1[16][32], red2[16][32];
  __shared__ float mu_s[32], ri_s[32];
  int st = blockIdx.x, b = blockIdx.y;
  int s0 = st * 32;
  int tid = threadIdx.x;
  int w = tid >> 6, l = tid & 63, lr = l & 15, lg = l >> 4;
  if (tid < 512) {
    int e = tid >> 5, i = tid & 31;
    invs[e][i] = inv[((size_t)(e * B_ + b)) * S_ + s0 + i];
  }
  __syncthreads();
  // stage all experts' A tiles: 4096 x 16B chunks, coalesced per row
#pragma unroll
  for (int p = 0; p < 4; p++) {
    int idx = p * 1024 + tid;
    int e = idx >> 8, rem = idx & 255;
    int row = rem >> 3, c = rem & 7;
    int m = invs[e][row];
    bf16x8 v;
    if (m >= 0) {
      v = *reinterpret_cast<const bf16x8*>(
          ctx + ((size_t)(e * B_ + b) * MAXLEN_ + m) * DH_ + c * 8);
    } else {
#pragma unroll
      for (int t = 0; t < 8; t++) v[t] = 0;
    }
    *reinterpret_cast<bf16x8*>(Ae_ + e * 4096 + swz128(row, c * 16)) = v;
  }
  __syncthreads();
  f32x4 acc[2][4];
#pragma unroll
  for (int a = 0; a < 2; a++)
#pragma unroll
    for (int j = 0; j < 4; j++) acc[a][j] = (f32x4){0.f, 0.f, 0.f, 0.f};
#pragma unroll 1
  for (int e = 0; e < E_; e++) {
    const char* Ab = Ae_ + e * 4096;
    bf16x8 af[2][2];
#pragma unroll
    for (int a = 0; a < 2; a++)
#pragma unroll
      for (int ks = 0; ks < 2; ks++)
        af[a][ks] = *reinterpret_cast<const bf16x8*>(
            Ab + swz128(a * 16 + lr, ks * 64 + lg * 16));
    const unsigned short* We = Wpk + (size_t)e * 65536;
#pragma unroll
    for (int j = 0; j < 4; j++) {
      int nbi = w * 4 + j;
      bf16x8 b0 = *reinterpret_cast<const bf16x8*>(We + (((size_t)nbi * 2 + 0) * 64 + l) * 8);
      bf16x8 b1 = *reinterpret_cast<const bf16x8*>(We + (((size_t)nbi * 2 + 1) * 64 + l) * 8);
      acc[0][j] = mfma16(af[0][0], b0, acc[0][j]);
      acc[1][j] = mfma16(af[1][0], b0, acc[1][j]);
      acc[0][j] = mfma16(af[0][1], b1, acc[0][j]);
      acc[1][j] = mfma16(af[1][1], b1, acc[1][j]);
    }
  }
  {
    bf16x8 afb[2];
#pragma unroll
    for (int a = 0; a < 2; a++) {
#pragma unroll
      for (int t = 0; t < 8; t++) {
        int k = lg * 8 + t;
        unsigned short u = 0;
        if (k < E_ && invs[k][a * 16 + lr] >= 0) u = 0x3F80;  // 1.0bf16
        afb[a][t] = (short)u;
      }
    }
#pragma unroll
    for (int j = 0; j < 4; j++) {
      int n = w * 64 + j * 16 + lr;
      bf16x8 bb = *reinterpret_cast<const bf16x8*>(bffT + (size_t)n * 32 + lg * 8);
      acc[0][j] = mfma16(afb[0], bb, acc[0][j]);
      acc[1][j] = mfma16(afb[1], bb, acc[1][j]);
    }
  }
  // epilogue: + X residual (loaded here), row stats, LayerNorm, store f32
  float p1[2][4], p2[2][4];
#pragma unroll
  for (int a = 0; a < 2; a++)
#pragma unroll
    for (int i = 0; i < 4; i++) { p1[a][i] = 0.f; p2[a][i] = 0.f; }
#pragma unroll
  for (int a = 0; a < 2; a++) {
#pragma unroll
    for (int j = 0; j < 4; j++) {
      int col = w * 64 + j * 16 + lr;
#pragma unroll
      for (int i = 0; i < 4; i++) {
        int row = a * 16 + lg * 4 + i;
        float x = X[((size_t)b * S_ + s0 + row) * D_ + col];
        float v = acc[a][j][i] + x;
        acc[a][j][i] = v;
        p1[a][i] += v;
        p2[a][i] += v * v;
      }
    }
  }
#pragma unroll
  for (int a = 0; a < 2; a++)
#pragma unroll
    for (int i = 0; i < 4; i++) {
#pragma unroll
      for (int off = 1; off < 16; off <<= 1) {
        p1[a][i] += __shfl_xor(p1[a][i], off);
        p2[a][i] += __shfl_xor(p2[a][i], off);
      }
    }
  if (lr == 0) {
#pragma unroll
    for (int a = 0; a < 2; a++)
#pragma unroll
      for (int i = 0; i < 4; i++) {
        int row = a * 16 + lg * 4 + i;
        red1[w][row] = p1[a][i];
        red2[w][row] = p2[a][i];
      }
  }
  __syncthreads();
  if (tid < 32) {
    float s1 = 0.f, s2 = 0.f;
#pragma unroll
    for (int w2 = 0; w2 < 16; w2++) { s1 += red1[w2][tid]; s2 += red2[w2][tid]; }
    float mu = s1 * (1.f / D_);
    float var = s2 * (1.f / D_) - mu * mu;
    mu_s[tid] = mu;
    ri_s[tid] = rsqrtf(var + 1e-5f);
  }
  __syncthreads();
#pragma unroll
  for (int a = 0; a < 2; a++) {
#pragma unroll
    for (int j = 0; j < 4; j++) {
      int col = w * 64 + j * 16 + lr;
      float g = gamma[col];
      float be = beta[col];
#pragma unroll
      for (int i = 0; i < 4; i++) {
        int row = a * 16 + lg * 4 + i;
        out[((size_t)b * S_ + s0 + row) * D_ + col] =
            (acc[a][j][i] - mu_s[row]) * ri_s[row] * g + be;
      }
    }
  }
}

extern "C" void kernel_launch(void* const* d_in, const int* in_sizes, int n_in,
                              void* d_out, int out_size, void* d_ws, size_t ws_size,
                              hipStream_t stream) {
  const float* X = (const float*)d_in[0];
  // d_in[1] = attn_mask (causal, hardcoded)
  const float* w_gate = (const float*)d_in[2];
  const float* b_gate = (const float*)d_in[3];
  const float* W_qkv = (const float*)d_in[4];
  const float* W_ff = (const float*)d_in[5];
  const float* b_ff = (const float*)d_in[6];
  const float* ln_g = (const float*)d_in[7];
  const float* ln_b = (const float*)d_in[8];
  float* out = (float*)d_out;

  char* ws = (char*)d_ws;
  float* masked_t = (float*)(ws);                           //   524288 B
  int* seq_ids = (int*)(ws + 1048576);                      //   314368 B
  unsigned short* Qr = (unsigned short*)(ws + 1362944);     // 10485760 B
  unsigned short* Kr = (unsigned short*)(ws + 11848704);    // 10485760 B
  unsigned short* VT = (unsigned short*)(ws + 22334464);    // 10485760 B
  unsigned short* ctx = (unsigned short*)(ws + 32820224);   // 10059776 B
  unsigned short* Xb16 = (unsigned short*)(ws + 42880000);  // 16777216 B
  unsigned short* Wtq = (unsigned short*)(ws + 59657216);   //  6291456 B
  unsigned short* Wpk = (unsigned short*)(ws + 65948672);   //  2097152 B
  float* wgT = (float*)(ws + 68045824);                     //    65536 B
  unsigned short* bffT = (unsigned short*)(ws + 68111360);  //    65536 B
  int* inv = (int*)(ws + 68176896);                         //   524288 B
  // total 68701184 B

  cvt_all_kernel<<<836, 256, 0, stream>>>(W_qkv, Wtq, W_ff, Wpk, w_gate, wgT,
                                          b_ff, bffT);
  gate_kernel<<<2048, 256, 0, stream>>>(X, wgT, b_gate, masked_t, Xb16);
  select_kernel<<<E_ * B_, 256, 0, stream>>>(masked_t, seq_ids, inv);
  qkv_kernel<<<dim3(10, 64), 512, 0, stream>>>(Xb16, Wtq, seq_ids, Qr, Kr, VT);
  attn_kernel<<<dim3(10, 64), 512, 0, stream>>>(Qr, Kr, VT, ctx);
  ffgl_kernel<<<dim3(S_ / 32, B_), 1024, 0, stream>>>(X, ctx, Wpk, bffT, inv,
                                                      ln_g, ln_b, out);
}

// Round 23
// 170.905 us; speedup vs baseline: 1.0486x; 1.0018x over previous
//
#include <hip/hip_runtime.h>
#include <math.h>

#define B_ 4
#define S_ 2048
#define D_ 1024
#define E_ 16
#define DH_ 64
#define TOPK_ 8
#define MAXLEN_ 1228
#define MPAD_ 1280
#define CAPF 4.0f
#define EPS_ 1e-6f
// Q scale with log2(e) folded in: 0.125 * 1.4426950408889634
#define QSCALE_ 0.18033688011112042f

typedef __attribute__((ext_vector_type(8))) short bf16x8;
typedef __attribute__((ext_vector_type(4))) float f32x4;

__device__ inline f32x4 mfma16(bf16x8 a, bf16x8 b, f32x4 c) {
  return __builtin_amdgcn_mfma_f32_16x16x32_bf16(a, b, c, 0, 0, 0);
}
__device__ inline float bf2f(unsigned short u) {
  return __uint_as_float(((unsigned)u) << 16);
}
__device__ inline unsigned short f2bf(float f) {
  unsigned u = __float_as_uint(f);
  unsigned r = (u + 0x7FFFu + ((u >> 16) & 1u)) >> 16;
  return (unsigned short)r;
}
__device__ inline unsigned cvtpk(float lo, float hi) {
  unsigned r;
  asm("v_cvt_pk_bf16_f32 %0, %1, %2" : "=v"(r) : "v"(lo), "v"(hi));
  return r;
}
// hardware 2^x (v_exp_f32 computes exp2)
__device__ inline float exp2x(float x) {
  float r;
  asm("v_exp_f32 %0, %1" : "=v"(r) : "v"(x));
  return r;
}
__device__ inline ushort4 pk4(float4 v) {
  ushort4 r;
  r.x = f2bf(v.x); r.y = f2bf(v.y); r.z = f2bf(v.z); r.w = f2bf(v.w);
  return r;
}
// XOR-swizzled LDS addressing (byte offsets), 128B rows.
__device__ inline int swz128(int row, int off) { return row * 128 + (off ^ ((row & 7) << 4)); }

// ---- Kernel 1: fused converts + gating (one launch) ----
// blocks [0,512):    W_qkv -> Wt
// blocks [512,768):  W_ff  -> Wpk
// blocks [768,832):  wg -> wgT
// blocks [832,836):  bff -> bffT
// blocks [836,1348): gate (16 tokens/block, 4 tokens/wave) + Xb16 emit
__global__ __launch_bounds__(256) void cvtgate_kernel(
    const float* __restrict__ Wq, unsigned short* __restrict__ Wt,
    const float* __restrict__ Wf, unsigned short* __restrict__ Wpk,
    const float* __restrict__ wg, float* __restrict__ wgT,
    const float* __restrict__ bff, unsigned short* __restrict__ bffT,
    const float* __restrict__ X, const float* __restrict__ bg,
    float* __restrict__ masked_t, unsigned short* __restrict__ Xb) {
  __shared__ short T[192][40];
  int bid = blockIdx.x;
  int tid = threadIdx.x;
  if (bid < 512) {
    int e = bid >> 5, k0 = (bid & 31) * 32;
    const float* Wp = Wq + (size_t)e * D_ * 192 + (size_t)k0 * 192;
#pragma unroll
    for (int it = 0; it < 24; it++) {
      int idx = tid + it * 256;  // 0..6143
      int kr = idx / 192, n = idx % 192;
      T[n][kr] = (short)f2bf(Wp[(size_t)kr * 192 + n]);
    }
    __syncthreads();
    unsigned short* Wo = Wt + (size_t)e * 192 * 1024 + k0;
#pragma unroll
    for (int it = 0; it < 3; it++) {
      int idx = tid + it * 256;  // 0..767
      int n = idx >> 2, c = idx & 3;
      bf16x8 v = *reinterpret_cast<bf16x8*>(&T[n][c * 8]);
      *reinterpret_cast<bf16x8*>(Wo + (size_t)n * 1024 + c * 8) = v;
    }
  } else if (bid < 768) {
    int l2 = bid - 512;
    int e = l2 >> 4;
    int nb = (l2 & 15) * 4 + (tid >> 6);
    int l = tid & 63;
    int lr = l & 15, lg = l >> 4;
    const float* Wp = Wf + (size_t)e * DH_ * D_;
#pragma unroll
    for (int ks = 0; ks < 2; ks++) {
      bf16x8 v;
#pragma unroll
      for (int j = 0; j < 8; j++) {
        int k = ks * 32 + lg * 8 + j;
        int n = nb * 16 + lr;
        v[j] = (short)f2bf(Wp[(size_t)k * D_ + n]);
      }
      *reinterpret_cast<bf16x8*>(Wpk + ((((size_t)e * 64 + nb) * 2 + ks) * 64 + l) * 8) = v;
    }
  } else if (bid < 832) {
    int idx = (bid - 768) * 256 + tid;  // 0..16383
    int e = idx >> 10, d = idx & 1023;
    wgT[idx] = wg[(size_t)d * E_ + e];
  } else if (bid < 836) {
    int n = (bid - 832) * 256 + tid;  // 0..1023
    unsigned short* o = bffT + (size_t)n * 32;
#pragma unroll
    for (int e = 0; e < E_; e++) o[e] = f2bf(bff[(size_t)e * D_ + n]);
#pragma unroll
    for (int e = E_; e < 32; e++) o[e] = 0;
  } else {
    // ---- gate: 4 tokens per wave; wgT loads reused x4 in registers ----
    int gbid = bid - 836;
    int wave = tid >> 6, lane = tid & 63;
    int tok0 = gbid * 16 + wave * 4;
    float vals[64];  // [t*16+e]
#pragma unroll
    for (int i = 0; i < 64; i++) vals[i] = 0.f;
#pragma unroll
    for (int d0 = 0; d0 < D_; d0 += 256) {
      int d = d0 + lane * 4;
      float4 xv[4];
#pragma unroll
      for (int t = 0; t < 4; t++) {
        xv[t] = *reinterpret_cast<const float4*>(X + (size_t)(tok0 + t) * D_ + d);
        *reinterpret_cast<ushort4*>(Xb + (size_t)(tok0 + t) * D_ + d) = pk4(xv[t]);
      }
#pragma unroll
      for (int e = 0; e < E_; e++) {
        float4 wv = *reinterpret_cast<const float4*>(wgT + (size_t)e * D_ + d);
#pragma unroll
        for (int t = 0; t < 4; t++)
          vals[t * 16 + e] += xv[t].x * wv.x + xv[t].y * wv.y +
                              xv[t].z * wv.z + xv[t].w * wv.w;
      }
    }
    // multi-value butterfly: lane l ends with full sum for index l
#pragma unroll
    for (int off = 32; off >= 1; off >>= 1) {
#pragma unroll
      for (int i = 0; i < 64; i++) {
        if (i < off) {
          float keep = (lane & off) ? vals[i + off] : vals[i];
          float send = (lane & off) ? vals[i] : vals[i + off];
          vals[i] = keep + __shfl_xor(send, off);
        }
      }
    }
    // tail: lane = t*16 + e
    int t = lane >> 4, e = lane & 15;
    int token = tok0 + t;
    int b = token / S_, s = token % S_;
    float lg = vals[0] + bg[e];
    float mx = lg;
#pragma unroll
    for (int off = 1; off < 16; off <<= 1) mx = fmaxf(mx, __shfl_xor(mx, off));
    float ex = expf(lg - mx);
    float den = ex;
#pragma unroll
    for (int off = 1; off < 16; off <<= 1) den += __shfl_xor(den, off);
    float sc = ex / den;
    int rank = 0;
#pragma unroll
    for (int j = 0; j < 16; j++) {
      float v = __shfl(lg, (lane & 48) + j);
      if (v > lg || (v == lg && j < e)) rank++;
    }
    float m = (rank < TOPK_) ? sc : 0.f;
    masked_t[((size_t)e * B_ + b) * S_ + s] = m;
  }
}

// ------- Kernel 3: radix-select top-MAXLEN per (e,b), route fused ------
// Also writes inv[eb][s] = m (or -1) directly (inv_kernel folded in).
__global__ __launch_bounds__(256) void select_kernel(
    const float* __restrict__ masked_t, int* __restrict__ seq_ids,
    int* __restrict__ inv) {
  __shared__ unsigned vals[S_];
  __shared__ int hist[256];
  __shared__ int wsum[4];
  __shared__ int tsum[4];
  __shared__ unsigned sh_prefix;
  __shared__ int sh_rank;
  int eb = blockIdx.x;
  int e = eb >> 2, b = eb & 3;
  int tid = threadIdx.x;
  int lane = tid & 63, wv = tid >> 6;
  const float* mb0 = masked_t + (size_t)e * B_ * S_;
  for (int i = tid; i < S_; i += 256) {
    float v0 = mb0[i];
    float v1 = mb0[S_ + i];
    float v2 = mb0[2 * S_ + i];
    float v3 = mb0[3 * S_ + i];
    float d = EPS_;
    d += v0; d += v1; d += v2; d += v3;  // same order as route_kernel
    float mv = mb0[(size_t)b * S_ + i];
    vals[i] = __float_as_uint(mv / d * CAPF);
  }
  if (tid == 0) { sh_prefix = 0u; sh_rank = MAXLEN_; }
  __syncthreads();
  for (int shift = 24; shift >= 0; shift -= 8) {
    hist[tid] = 0;
    __syncthreads();
    unsigned pfx = sh_prefix;
    unsigned maskhi = (shift == 24) ? 0u : (0xFFFFFFFFu << (shift + 8));
    for (int i = tid; i < S_; i += 256) {
      unsigned v = vals[i];
      if ((v & maskhi) == pfx) atomicAdd(&hist[(v >> shift) & 255], 1);
    }
    __syncthreads();
    int bin = 255 - tid;
    int h = hist[bin];
    int sc = h;
    for (int off = 1; off < 64; off <<= 1) {
      int n = __shfl_up(sc, off);
      if (lane >= off) sc += n;
    }
    if (lane == 63) wsum[wv] = sc;
    __syncthreads();
    int add = 0;
#pragma unroll
    for (int k = 0; k < 4; k++)
      if (k < wv) add += wsum[k];
    sc += add;
    int rank = sh_rank;
    __syncthreads();
    if (sc - h < rank && rank <= sc) {
      sh_prefix = pfx | ((unsigned)bin << shift);
      sh_rank = rank - (sc - h);
    }
    __syncthreads();
  }
  unsigned T = sh_prefix;
  int r = sh_rank;
  int i0 = tid * 8;
  int eqf[8], gtf[8];
  int eqtot = 0;
#pragma unroll
  for (int k = 0; k < 8; k++) {
    unsigned v = vals[i0 + k];
    eqf[k] = (v == T) ? 1 : 0;
    gtf[k] = (v > T) ? 1 : 0;
    eqtot += eqf[k];
  }
  int esc = eqtot;
  for (int off = 1; off < 64; off <<= 1) {
    int n = __shfl_up(esc, off);
    if (lane >= off) esc += n;
  }
  if (lane == 63) tsum[wv] = esc;
  __syncthreads();
  int eadd = 0;
#pragma unroll
  for (int k = 0; k < 4; k++)
    if (k < wv) eadd += tsum[k];
  int erun = esc - eqtot + eadd;
  int self_[8];
  int stot = 0;
#pragma unroll
  for (int k = 0; k < 8; k++) {
    int s = gtf[k] | (eqf[k] & (erun < r ? 1 : 0));
    erun += eqf[k];
    self_[k] = s;
    stot += s;
  }
  __syncthreads();
  int ssc = stot;
  for (int off = 1; off < 64; off <<= 1) {
    int n = __shfl_up(ssc, off);
    if (lane >= off) ssc += n;
  }
  if (lane == 63) tsum[wv] = ssc;
  __syncthreads();
  int sadd = 0;
#pragma unroll
  for (int k = 0; k < 4; k++)
    if (k < wv) sadd += tsum[k];
  int pos = ssc - stot + sadd;
  int* outp = seq_ids + (size_t)eb * MAXLEN_;
  int* ip = inv + (size_t)eb * S_;
#pragma unroll
  for (int k = 0; k < 8; k++) {
    if (self_[k]) {
      outp[pos] = i0 + k;
      ip[i0 + k] = pos;
      pos++;
    } else {
      ip[i0 + k] = -1;
    }
  }
}

// ---------------- Kernel 4: gathered QKV GEMM (bf16 MFMA) ----------------
// v6 (R20): A+B staged through LDS (40 KB), single-buffered, register
// prefetch across the barrier; row ids loaded directly from seq_ids.
__global__ __launch_bounds__(512) void qkv_kernel(
    const unsigned short* __restrict__ Xb, const unsigned short* __restrict__ Wt,
    const int* __restrict__ seq_ids, unsigned short* __restrict__ Qr,
    unsigned short* __restrict__ Kr, unsigned short* __restrict__ VT) {
  __shared__ __align__(16) char Bs_[192 * 128];  // [192 n][64 k] bf16 swz128
  __shared__ __align__(16) char As_[128 * 128];  // [128 m][64 k] bf16 swz128
  int eb = blockIdx.y;
  int e = eb >> 2, b = eb & 3;
  int m0 = blockIdx.x * 128;
  int tid = threadIdx.x;
  int w = tid >> 6, l = tid & 63, lr = l & 15, lg = l >> 4;
  int wm = w & 3, wn = w >> 2;
  const int* sid = seq_ids + (size_t)eb * MAXLEN_;
  const unsigned short* Wm = Wt + (size_t)e * 192 * 1024;
  const unsigned short* Xbb = Xb + (size_t)b * S_ * D_;
  int b0r = tid >> 3, b0c = tid & 7;
  int b1r = (tid + 512) >> 3, b1c = b0c;
  int b2r = (tid + 1024) >> 3, b2c = b0c;
  int a0r = b0r, a0c = b0c;        // A rows 0..63
  int a1r = b1r, a1c = b0c;        // A rows 64..127
  int am0 = m0 + a0r, am1 = m0 + a1r;
  int r0 = (am0 < MAXLEN_) ? sid[am0] : 0;   // 8 threads share each entry
  int r1 = (am1 < MAXLEN_) ? sid[am1] : 0;
  const unsigned short* bpp0 = Wm + (size_t)b0r * 1024 + b0c * 8;
  const unsigned short* bpp1 = Wm + (size_t)b1r * 1024 + b1c * 8;
  const unsigned short* bpp2 = Wm + (size_t)b2r * 1024 + b2c * 8;
  const unsigned short* app0 = Xbb + (size_t)r0 * D_ + a0c * 8;
  const unsigned short* app1 = Xbb + (size_t)r1 * D_ + a1c * 8;
  f32x4 acc[2][6];
#pragma unroll
  for (int a = 0; a < 2; a++)
#pragma unroll
    for (int j = 0; j < 6; j++) acc[a][j] = (f32x4){0.f, 0.f, 0.f, 0.f};
  bf16x8 sb0 = *reinterpret_cast<const bf16x8*>(bpp0);
  bf16x8 sb1 = *reinterpret_cast<const bf16x8*>(bpp1);
  bf16x8 sb2 = *reinterpret_cast<const bf16x8*>(bpp2);
  bf16x8 sa0 = *reinterpret_cast<const bf16x8*>(app0);
  bf16x8 sa1 = *reinterpret_cast<const bf16x8*>(app1);
  for (int t = 0; t < 16; t++) {
    __syncthreads();  // readers of tile t-1 done (no-op at t=0)
    *reinterpret_cast<bf16x8*>(Bs_ + swz128(b0r, b0c * 16)) = sb0;
    *reinterpret_cast<bf16x8*>(Bs_ + swz128(b1r, b1c * 16)) = sb1;
    *reinterpret_cast<bf16x8*>(Bs_ + swz128(b2r, b2c * 16)) = sb2;
    *reinterpret_cast<bf16x8*>(As_ + swz128(a0r, a0c * 16)) = sa0;
    *reinterpret_cast<bf16x8*>(As_ + swz128(a1r, a1c * 16)) = sa1;
    __syncthreads();  // writes visible
    if (t < 15) {
      int kn = (t + 1) * 64;
      sb0 = *reinterpret_cast<const bf16x8*>(bpp0 + kn);
      sb1 = *reinterpret_cast<const bf16x8*>(bpp1 + kn);
      sb2 = *reinterpret_cast<const bf16x8*>(bpp2 + kn);
      sa0 = *reinterpret_cast<const bf16x8*>(app0 + kn);
      sa1 = *reinterpret_cast<const bf16x8*>(app1 + kn);
    }
    bf16x8 af[2][2];
#pragma unroll
    for (int a = 0; a < 2; a++)
#pragma unroll
      for (int ks = 0; ks < 2; ks++)
        af[a][ks] = *reinterpret_cast<bf16x8*>(
            As_ + swz128(wm * 32 + a * 16 + lr, ks * 64 + lg * 16));
#pragma unroll
    for (int j = 0; j < 6; j++) {
      int nr = (wn * 6 + j) * 16 + lr;
      bf16x8 bf0 = *reinterpret_cast<bf16x8*>(Bs_ + swz128(nr, lg * 16));
      bf16x8 bf1 = *reinterpret_cast<bf16x8*>(Bs_ + swz128(nr, 64 + lg * 16));
      acc[0][j] = mfma16(af[0][0], bf0, acc[0][j]);
      acc[1][j] = mfma16(af[1][0], bf0, acc[1][j]);
      acc[0][j] = mfma16(af[0][1], bf1, acc[0][j]);
      acc[1][j] = mfma16(af[1][1], bf1, acc[1][j]);
    }
  }
  unsigned short* Qe = Qr + (size_t)eb * MPAD_ * 64;
  unsigned short* Ke = Kr + (size_t)eb * MPAD_ * 64;
  unsigned short* Ve = VT + (size_t)eb * 64 * MPAD_;
#pragma unroll
  for (int a = 0; a < 2; a++) {
    int mb = m0 + wm * 32 + a * 16 + lg * 4;
#pragma unroll
    for (int j = 0; j < 6; j++) {
      int nbg = wn * 6 + j;
      if (nbg < 4) {
#pragma unroll
        for (int i = 0; i < 4; i++) {
          int m = mb + i;
          float v = (m < MAXLEN_) ? acc[a][j][i] * QSCALE_ : 0.f;
          Qe[(size_t)m * 64 + nbg * 16 + lr] = f2bf(v);
        }
      } else if (nbg < 8) {
#pragma unroll
        for (int i = 0; i < 4; i++) {
          int m = mb + i;
          float v = (m < MAXLEN_) ? acc[a][j][i] : 0.f;
          Ke[(size_t)m * 64 + (nbg - 4) * 16 + lr] = f2bf(v);
        }
      } else {
        ushort4 pv;
        pv.x = (mb + 0 < MAXLEN_) ? f2bf(acc[a][j][0]) : (unsigned short)0;
        pv.y = (mb + 1 < MAXLEN_) ? f2bf(acc[a][j][1]) : (unsigned short)0;
        pv.z = (mb + 2 < MAXLEN_) ? f2bf(acc[a][j][2]) : (unsigned short)0;
        pv.w = (mb + 3 < MAXLEN_) ? f2bf(acc[a][j][3]) : (unsigned short)0;
        *reinterpret_cast<ushort4*>(Ve + (size_t)((nbg - 8) * 16 + lr) * MPAD_ + mb) = pv;
      }
    }
  }
}

// ------------- Kernel 5: flash attention, bf16 MFMA, per (e,b) -------------
// exp2-softmax; P repack via v_cvt_pk_bf16_f32; K/V register prefetch
// across the barrier (loads for tile t+1 fly during tile-t compute).
__global__ __launch_bounds__(512) void attn_kernel(
    const unsigned short* __restrict__ Qr, const unsigned short* __restrict__ Kr,
    const unsigned short* __restrict__ VT, unsigned short* __restrict__ ctx) {
  __shared__ __align__(16) char Ks_[64 * 128];      // [64 k][64 d] swz128
  __shared__ __align__(16) char Vt_[64 * 128];      // [64 dv][64 k] swz128
  __shared__ __align__(16) char Pl_[8 * 16 * 128];  // per-wave [16 q][64 k]
  int qb = 9 - blockIdx.x;  // longest first
  int eb = blockIdx.y;
  const unsigned short* Qe = Qr + (size_t)eb * MPAD_ * 64;
  const unsigned short* Ke = Kr + (size_t)eb * MPAD_ * 64;
  const unsigned short* Ve = VT + (size_t)eb * 64 * MPAD_;
  int tid = threadIdx.x;
  int w = tid >> 6, l = tid & 63, lr = l & 15, lg = l >> 4;
  int gq = qb * 128 + w * 16 + lr;
  bf16x8 qf[2];
  qf[0] = *reinterpret_cast<const bf16x8*>(Qe + (size_t)gq * 64 + lg * 8);
  qf[1] = *reinterpret_cast<const bf16x8*>(Qe + (size_t)gq * 64 + 32 + lg * 8);
  f32x4 acc[4];
#pragma unroll
  for (int db = 0; db < 4; db++) acc[db] = (f32x4){0.f, 0.f, 0.f, 0.f};
  float mrow = -1e30f, lsum = 0.f;
  char* Pw = Pl_ + w * 2048;
  int srow = tid >> 3, sc = (tid & 7) * 8;
  int ndiag = 2 * qb, ktmax = 2 * qb + 1;
  // prologue: tile 0 into regs
  bf16x8 skv = *reinterpret_cast<const bf16x8*>(Ke + (size_t)srow * 64 + sc);
  bf16x8 svv = *reinterpret_cast<const bf16x8*>(Ve + (size_t)srow * MPAD_ + sc);
  for (int kt = 0; kt <= ktmax; kt++) {
    int k0 = kt * 64;
    __syncthreads();  // readers of tile t-1 done (no-op at kt=0)
    *reinterpret_cast<bf16x8*>(Ks_ + swz128(srow, sc * 2)) = skv;
    *reinterpret_cast<bf16x8*>(Vt_ + swz128(srow, sc * 2)) = svv;
    __syncthreads();  // writes visible
    if (kt < ktmax) {  // prefetch t+1; in flight across compute
      int kn = k0 + 64;
      skv = *reinterpret_cast<const bf16x8*>(Ke + (size_t)(kn + srow) * 64 + sc);
      svv = *reinterpret_cast<const bf16x8*>(Ve + (size_t)srow * MPAD_ + kn + sc);
    }
    f32x4 sac[4];
#pragma unroll
    for (int kb = 0; kb < 4; kb++) {
      sac[kb] = (f32x4){0.f, 0.f, 0.f, 0.f};
#pragma unroll
      for (int ds = 0; ds < 2; ds++) {
        bf16x8 kf = *reinterpret_cast<bf16x8*>(Ks_ + swz128(kb * 16 + lr, ds * 64 + lg * 16));
        sac[kb] = mfma16(kf, qf[ds], sac[kb]);
      }
    }
    float p[16];
    float tmax = -1e30f;
    if (kt >= ndiag) {
#pragma unroll
      for (int kb = 0; kb < 4; kb++) {
#pragma unroll
        for (int i = 0; i < 4; i++) {
          int k = k0 + kb * 16 + lg * 4 + i;
          float s = sac[kb][i];
          if (k > gq || k >= MAXLEN_) s = -1e9f;
          p[kb * 4 + i] = s;
          tmax = fmaxf(tmax, s);
        }
      }
    } else {
#pragma unroll
      for (int kb = 0; kb < 4; kb++) {
#pragma unroll
        for (int i = 0; i < 4; i++) {
          float s = sac[kb][i];
          p[kb * 4 + i] = s;
          tmax = fmaxf(tmax, s);
        }
      }
    }
    tmax = fmaxf(tmax, __shfl_xor(tmax, 16));
    tmax = fmaxf(tmax, __shfl_xor(tmax, 32));
    if (!__all(tmax <= mrow + 8.f)) {  // defer-rescale (log2 units)
      float mnew = fmaxf(mrow, tmax);
      float corr = exp2x(mrow - mnew);
      lsum *= corr;
#pragma unroll
      for (int db = 0; db < 4; db++) acc[db] = acc[db] * corr;
      mrow = mnew;
    }
    float psum = 0.f;
#pragma unroll
    for (int j = 0; j < 16; j++) {
      p[j] = exp2x(p[j] - mrow);
      psum += p[j];
    }
    psum += __shfl_xor(psum, 16);
    psum += __shfl_xor(psum, 32);
    lsum += psum;
#pragma unroll
    for (int kb = 0; kb < 4; kb++) {
#pragma unroll
      for (int ip = 0; ip < 2; ip++) {
        unsigned u = cvtpk(p[kb * 4 + ip * 2], p[kb * 4 + ip * 2 + 1]);
        int k = kb * 16 + lg * 4 + ip * 2;
        *reinterpret_cast<unsigned*>(Pw + swz128(lr, k * 2)) = u;
      }
    }
    bf16x8 pf[2];
#pragma unroll
    for (int ks = 0; ks < 2; ks++)
      pf[ks] = *reinterpret_cast<bf16x8*>(Pw + swz128(lr, ks * 64 + lg * 16));
#pragma unroll
    for (int db = 0; db < 4; db++) {
#pragma unroll
      for (int ks = 0; ks < 2; ks++) {
        bf16x8 vf = *reinterpret_cast<bf16x8*>(Vt_ + swz128(db * 16 + lr, ks * 64 + lg * 16));
        acc[db] = mfma16(vf, pf[ks], acc[db]);
      }
    }
  }
  if (gq < MAXLEN_) {
    float inv = 1.f / lsum;
    unsigned short* op = ctx + ((size_t)eb * MAXLEN_ + gq) * DH_;
#pragma unroll
    for (int db = 0; db < 4; db++) {
      uint2 pv;
      pv.x = cvtpk(acc[db][0] * inv, acc[db][1] * inv);
      pv.y = cvtpk(acc[db][2] * inv, acc[db][3] * inv);
      *reinterpret_cast<uint2*>(op + db * 16 + lg * 4) = pv;
    }
  }
}

// --- Kernel 6: fused FF + expert-sum + residual + LayerNorm ---
// v4 (R15): ALL experts' A-tiles staged to LDS up front (64KB, one barrier),
// then the 16-expert MFMA loop runs with ZERO barriers.
__global__ __launch_bounds__(1024) void ffgl_kernel(
    const float* __restrict__ X, const unsigned short* __restrict__ ctx,
    const unsigned short* __restrict__ Wpk, const unsigned short* __restrict__ bffT,
    const int* __restrict__ inv, const float* __restrict__ gamma,
    const float* __restrict__ beta, float* __restrict__ out) {
  __shared__ int invs[E_][32];
  __shared__ __align__(16) char Ae_[E_ * 32 * 128];  // 64 KB
  __shared__ float red1[16][32], red2[16][32];
  __shared__ float mu_s[32], ri_s[32];
  int st = blockIdx.x, b = blockIdx.y;
  int s0 = st * 32;
  int tid = threadIdx.x;
  int w = tid >> 6, l = tid & 63, lr = l & 15, lg = l >> 4;
  if (tid < 512) {
    int e = tid >> 5, i = tid & 31;
    invs[e][i] = inv[((size_t)(e * B_ + b)) * S_ + s0 + i];
  }
  __syncthreads();
  // stage all experts' A tiles: 4096 x 16B chunks, coalesced per row
#pragma unroll
  for (int p = 0; p < 4; p++) {
    int idx = p * 1024 + tid;
    int e = idx >> 8, rem = idx & 255;
    int row = rem >> 3, c = rem & 7;
    int m = invs[e][row];
    bf16x8 v;
    if (m >= 0) {
      v = *reinterpret_cast<const bf16x8*>(
          ctx + ((size_t)(e * B_ + b) * MAXLEN_ + m) * DH_ + c * 8);
    } else {
#pragma unroll
      for (int t = 0; t < 8; t++) v[t] = 0;
    }
    *reinterpret_cast<bf16x8*>(Ae_ + e * 4096 + swz128(row, c * 16)) = v;
  }
  __syncthreads();
  f32x4 acc[2][4];
#pragma unroll
  for (int a = 0; a < 2; a++)
#pragma unroll
    for (int j = 0; j < 4; j++) acc[a][j] = (f32x4){0.f, 0.f, 0.f, 0.f};
#pragma unroll 1
  for (int e = 0; e < E_; e++) {
    const char* Ab = Ae_ + e * 4096;
    bf16x8 af[2][2];
#pragma unroll
    for (int a = 0; a < 2; a++)
#pragma unroll
      for (int ks = 0; ks < 2; ks++)
        af[a][ks] = *reinterpret_cast<const bf16x8*>(
            Ab + swz128(a * 16 + lr, ks * 64 + lg * 16));
    const unsigned short* We = Wpk + (size_t)e * 65536;
#pragma unroll
    for (int j = 0; j < 4; j++) {
      int nbi = w * 4 + j;
      bf16x8 b0 = *reinterpret_cast<const bf16x8*>(We + (((size_t)nbi * 2 + 0) * 64 + l) * 8);
      bf16x8 b1 = *reinterpret_cast<const bf16x8*>(We + (((size_t)nbi * 2 + 1) * 64 + l) * 8);
      acc[0][j] = mfma16(af[0][0], b0, acc[0][j]);
      acc[1][j] = mfma16(af[1][0], b0, acc[1][j]);
      acc[0][j] = mfma16(af[0][1], b1, acc[0][j]);
      acc[1][j] = mfma16(af[1][1], b1, acc[1][j]);
    }
  }
  {
    bf16x8 afb[2];
#pragma unroll
    for (int a = 0; a < 2; a++) {
#pragma unroll
      for (int t = 0; t < 8; t++) {
        int k = lg * 8 + t;
        unsigned short u = 0;
        if (k < E_ && invs[k][a * 16 + lr] >= 0) u = 0x3F80;  // 1.0bf16
        afb[a][t] = (short)u;
      }
    }
#pragma unroll
    for (int j = 0; j < 4; j++) {
      int n = w * 64 + j * 16 + lr;
      bf16x8 bb = *reinterpret_cast<const bf16x8*>(bffT + (size_t)n * 32 + lg * 8);
      acc[0][j] = mfma16(afb[0], bb, acc[0][j]);
      acc[1][j] = mfma16(afb[1], bb, acc[1][j]);
    }
  }
  // epilogue: + X residual (loaded here), row stats, LayerNorm, store f32
  float p1[2][4], p2[2][4];
#pragma unroll
  for (int a = 0; a < 2; a++)
#pragma unroll
    for (int i = 0; i < 4; i++) { p1[a][i] = 0.f; p2[a][i] = 0.f; }
#pragma unroll
  for (int a = 0; a < 2; a++) {
#pragma unroll
    for (int j = 0; j < 4; j++) {
      int col = w * 64 + j * 16 + lr;
#pragma unroll
      for (int i = 0; i < 4; i++) {
        int row = a * 16 + lg * 4 + i;
        float x = X[((size_t)b * S_ + s0 + row) * D_ + col];
        float v = acc[a][j][i] + x;
        acc[a][j][i] = v;
        p1[a][i] += v;
        p2[a][i] += v * v;
      }
    }
  }
#pragma unroll
  for (int a = 0; a < 2; a++)
#pragma unroll
    for (int i = 0; i < 4; i++) {
#pragma unroll
      for (int off = 1; off < 16; off <<= 1) {
        p1[a][i] += __shfl_xor(p1[a][i], off);
        p2[a][i] += __shfl_xor(p2[a][i], off);
      }
    }
  if (lr == 0) {
#pragma unroll
    for (int a = 0; a < 2; a++)
#pragma unroll
      for (int i = 0; i < 4; i++) {
        int row = a * 16 + lg * 4 + i;
        red1[w][row] = p1[a][i];
        red2[w][row] = p2[a][i];
      }
  }
  __syncthreads();
  if (tid < 32) {
    float s1 = 0.f, s2 = 0.f;
#pragma unroll
    for (int w2 = 0; w2 < 16; w2++) { s1 += red1[w2][tid]; s2 += red2[w2][tid]; }
    float mu = s1 * (1.f / D_);
    float var = s2 * (1.f / D_) - mu * mu;
    mu_s[tid] = mu;
    ri_s[tid] = rsqrtf(var + 1e-5f);
  }
  __syncthreads();
#pragma unroll
  for (int a = 0; a < 2; a++) {
#pragma unroll
    for (int j = 0; j < 4; j++) {
      int col = w * 64 + j * 16 + lr;
      float g = gamma[col];
      float be = beta[col];
#pragma unroll
      for (int i = 0; i < 4; i++) {
        int row = a * 16 + lg * 4 + i;
        out[((size_t)b * S_ + s0 + row) * D_ + col] =
            (acc[a][j][i] - mu_s[row]) * ri_s[row] * g + be;
      }
    }
  }
}

extern "C" void kernel_launch(void* const* d_in, const int* in_sizes, int n_in,
                              void* d_out, int out_size, void* d_ws, size_t ws_size,
                              hipStream_t stream) {
  const float* X = (const float*)d_in[0];
  // d_in[1] = attn_mask (causal, hardcoded)
  const float* w_gate = (const float*)d_in[2];
  const float* b_gate = (const float*)d_in[3];
  const float* W_qkv = (const float*)d_in[4];
  const float* W_ff = (const float*)d_in[5];
  const float* b_ff = (const float*)d_in[6];
  const float* ln_g = (const float*)d_in[7];
  const float* ln_b = (const float*)d_in[8];
  float* out = (float*)d_out;

  char* ws = (char*)d_ws;
  float* masked_t = (float*)(ws);                           //   524288 B
  int* seq_ids = (int*)(ws + 1048576);                      //   314368 B
  unsigned short* Qr = (unsigned short*)(ws + 1362944);     // 10485760 B
  unsigned short* Kr = (unsigned short*)(ws + 11848704);    // 10485760 B
  unsigned short* VT = (unsigned short*)(ws + 22334464);    // 10485760 B
  unsigned short* ctx = (unsigned short*)(ws + 32820224);   // 10059776 B
  unsigned short* Xb16 = (unsigned short*)(ws + 42880000);  // 16777216 B
  unsigned short* Wtq = (unsigned short*)(ws + 59657216);   //  6291456 B
  unsigned short* Wpk = (unsigned short*)(ws + 65948672);   //  2097152 B
  float* wgT = (float*)(ws + 68045824);                     //    65536 B
  unsigned short* bffT = (unsigned short*)(ws + 68111360);  //    65536 B
  int* inv = (int*)(ws + 68176896);                         //   524288 B
  // total 68701184 B

  cvtgate_kernel<<<1348, 256, 0, stream>>>(W_qkv, Wtq, W_ff, Wpk, w_gate, wgT,
                                           b_ff, bffT, X, b_gate, masked_t,
                                           Xb16);
  select_kernel<<<E_ * B_, 256, 0, stream>>>(masked_t, seq_ids, inv);
  qkv_kernel<<<dim3(10, 64), 512, 0, stream>>>(Xb16, Wtq, seq_ids, Qr, Kr, VT);
  attn_kernel<<<dim3(10, 64), 512, 0, stream>>>(Qr, Kr, VT, ctx);
  ffgl_kernel<<<dim3(S_ / 32, B_), 1024, 0, stream>>>(X, ctx, Wpk, bffT, inv,
                                                      ln_g, ln_b, out);
}